// Round 11
// baseline (723.652 us; speedup 1.0000x reference)
//
#include <hip/hip_runtime.h>
#include <hip/hip_bf16.h>

#define B_ 32
#define L_ 256
#define W_ 32
#define TILE 16
#define PSTR 40          // shorts per (row,col) position: 80B = 5*16B, b128-aligned
#define LL (L_*L_)

typedef float    floatx4 __attribute__((ext_vector_type(4)));
typedef float    floatx2 __attribute__((ext_vector_type(2)));
typedef short    shortx8 __attribute__((ext_vector_type(8)));
typedef unsigned uintx2  __attribute__((ext_vector_type(2)));
typedef unsigned uintx4  __attribute__((ext_vector_type(4)));

typedef const __attribute__((address_space(1))) unsigned guint_t;
typedef __attribute__((address_space(3))) unsigned luint_t;

// async global->LDS DMA, 16B per lane; LDS image linear in granule index.
// NOTE (r10 lesson): EXEC mask must be a contiguous prefix of the wave —
// interior holes shift the first-active-lane-derived LDS base (corrupt staging).
__device__ __forceinline__ void lds_dma16(const unsigned short* src, unsigned short* dst) {
    __builtin_amdgcn_global_load_lds((guint_t*)src, (luint_t*)dst, 16, 0, 0);
}

__device__ __forceinline__ floatx2 fma2(floatx2 a, floatx2 b, floatx2 c) {
#if __has_builtin(__builtin_elementwise_fma)
    return __builtin_elementwise_fma(a, b, c);
#else
    return floatx2{fmaf(a.x, b.x, c.x), fmaf(a.y, b.y, c.y)};
#endif
}

#if __has_builtin(__builtin_amdgcn_cvt_pk_bf16_f32)
__device__ __forceinline__ unsigned pack_bf2(float a, float b) {
    auto v = __builtin_amdgcn_cvt_pk_bf16_f32(a, b);
    return __builtin_bit_cast(unsigned, v);
}
#else
__device__ __forceinline__ unsigned pack_bf2(float a, float b) {
    unsigned ua = __float_as_uint(a);
    unsigned ub = __float_as_uint(b);
    ua += 0x7fffu + ((ua >> 16) & 1u);
    ub += 0x7fffu + ((ub >> 16) & 1u);
    return (ua >> 16) | (ub & 0xffff0000u);
}
#endif

// ---- fast GELU pair, sigmoid form; float2 polynomial ----
__device__ __forceinline__ unsigned gelu2_pack(floatx2 x) {
    floatx2 x2    = x * x;
    floatx2 t     = x2 * 0.044715f;
    floatx2 inner = fma2(t, x, x);
    floatx2 z     = inner * -2.3022082299446597f;
    float e0 = __builtin_amdgcn_exp2f(z.x);
    float e1 = __builtin_amdgcn_exp2f(z.y);
    float r0 = __builtin_amdgcn_rcpf(1.0f + e0);
    float r1 = __builtin_amdgcn_rcpf(1.0f + e1);
    floatx2 g = x * floatx2{r0, r1};
    return pack_bf2(g.x, g.y);
}

__device__ __forceinline__ int swizzle_blk(int p) {
    return (p & 7) * 1024 + (p >> 3);
}

// 9-tap dual-half MFMA conv; bias enters as the C operand of the FIRST mfma.
__device__ __forceinline__ void conv9(
        const shortx8& t00, const shortx8& t01, const shortx8& t02,
        const shortx8& t10, const shortx8& t11, const shortx8& t12,
        const shortx8& t20, const shortx8& t21, const shortx8& t22,
        const shortx8 af[3][2], const floatx4 bvv[2], floatx4 acc[2]) {
    #pragma unroll
    for (int h = 0; h < 2; ++h) {
        acc[h] = __builtin_amdgcn_mfma_f32_16x16x32_bf16(af[0][h], t11, bvv[h], 0, 0, 0);
        acc[h] = __builtin_amdgcn_mfma_f32_16x16x32_bf16(af[1][h], t01, acc[h], 0, 0, 0);
        acc[h] = __builtin_amdgcn_mfma_f32_16x16x32_bf16(af[1][h], t21, acc[h], 0, 0, 0);
        acc[h] = __builtin_amdgcn_mfma_f32_16x16x32_bf16(af[1][h], t10, acc[h], 0, 0, 0);
        acc[h] = __builtin_amdgcn_mfma_f32_16x16x32_bf16(af[1][h], t12, acc[h], 0, 0, 0);
        acc[h] = __builtin_amdgcn_mfma_f32_16x16x32_bf16(af[2][h], t00, acc[h], 0, 0, 0);
        acc[h] = __builtin_amdgcn_mfma_f32_16x16x32_bf16(af[2][h], t02, acc[h], 0, 0, 0);
        acc[h] = __builtin_amdgcn_mfma_f32_16x16x32_bf16(af[2][h], t20, acc[h], 0, 0, 0);
        acc[h] = __builtin_amdgcn_mfma_f32_16x16x32_bf16(af[2][h], t22, acc[h], 0, 0, 0);
    }
}

// Dual-site conv: per-site MFMA order identical to conv9; bias folded into first mfma.
__device__ __forceinline__ void conv9x2(
        const shortx8 r0[3], const shortx8 r1[3],
        const shortx8 r2[3], const shortx8 r3[3],
        const shortx8 af[3][2], const floatx4 bvv[2],
        floatx4 accA[2], floatx4 accB[2]) {
    const shortx8* ra[3] = { r0, r1, r2 };
    const shortx8* rb[3] = { r1, r2, r3 };
    const int F[9] = {0,1,1,1,1,2,2,2,2};
    const int R[9] = {1,0,2,1,1,0,0,2,2};
    const int C[9] = {1,1,1,0,2,0,2,0,2};
    #pragma unroll
    for (int k = 0; k < 9; ++k)
      #pragma unroll
      for (int h = 0; h < 2; ++h) {
        accA[h] = __builtin_amdgcn_mfma_f32_16x16x32_bf16(af[F[k]][h], ra[R[k]][C[k]],
                      (k == 0) ? bvv[h] : accA[h], 0, 0, 0);
        accB[h] = __builtin_amdgcn_mfma_f32_16x16x32_bf16(af[F[k]][h], rb[R[k]][C[k]],
                      (k == 0) ? bvv[h] : accB[h], 0, 0, 0);
      }
}

// Dual-site conv for the last layer (single half, zero C), same op table.
__device__ __forceinline__ void conv9x2_last(
        const shortx8 r0[3], const shortx8 r1[3],
        const shortx8 r2[3], const shortx8 r3[3],
        const shortx8 afl[3], const floatx4& zc, floatx4& accA, floatx4& accB) {
    const shortx8* ra[3] = { r0, r1, r2 };
    const shortx8* rb[3] = { r1, r2, r3 };
    const int F[9] = {0,1,1,1,1,2,2,2,2};
    const int R[9] = {1,0,2,1,1,0,0,2,2};
    const int C[9] = {1,1,1,0,2,0,2,0,2};
    #pragma unroll
    for (int k = 0; k < 9; ++k) {
        accA = __builtin_amdgcn_mfma_f32_16x16x32_bf16(afl[F[k]], ra[R[k]][C[k]],
                   (k == 0) ? zc : accA, 0, 0, 0);
        accB = __builtin_amdgcn_mfma_f32_16x16x32_bf16(afl[F[k]], rb[R[k]][C[k]],
                   (k == 0) ? zc : accB, 0, 0, 0);
    }
}

__device__ __forceinline__ void gelu_pack4(const floatx4 acc[2], unsigned d[4]) {
    d[0] = gelu2_pack(floatx2{acc[0][0], acc[0][1]});
    d[1] = gelu2_pack(floatx2{acc[0][2], acc[0][3]});
    d[2] = gelu2_pack(floatx2{acc[1][0], acc[1][1]});
    d[3] = gelu2_pack(floatx2{acc[1][2], acc[1][3]});
}

__device__ __forceinline__ void build_afrag(
        const float* wc, const float* wb, const float* wa, const float* bias,
        int m, int q, shortx8 af[3][2], floatx4 bvv[2]) {
    const float* wm[3] = { wc, wb, wa };
    #pragma unroll
    for (int f = 0; f < 3; ++f)
      #pragma unroll
      for (int h = 0; h < 2; ++h) {
        const float* row = wm[f] + (h*16 + m) * W_ + q*8;
        floatx4 r0 = *(const floatx4*)(row);
        floatx4 r1 = *(const floatx4*)(row + 4);
        union { shortx8 s; unsigned u[4]; } w;
        w.u[0] = pack_bf2(r0.x, r0.y);
        w.u[1] = pack_bf2(r0.z, r0.w);
        w.u[2] = pack_bf2(r1.x, r1.y);
        w.u[3] = pack_bf2(r1.z, r1.w);
        af[f][h] = w.s;
      }
    #pragma unroll
    for (int h = 0; h < 2; ++h)
        bvv[h] = *(const floatx4*)(bias + h*16 + q*4);
}

// ---------------- first layer: 1 channel -> 32 channels (site-major out) ----------------
__global__ __launch_bounds__(256) void kern_first(
        const float* __restrict__ x, float scale,
        const float* __restrict__ ci, const float* __restrict__ bi,
        const float* __restrict__ ai, const float* __restrict__ bias_i,
        unsigned short* __restrict__ hout) {
    __shared__ float tile[18*18];
    __shared__ float wC[W_], wB[W_], wA[W_], bs[W_];
    int blk = swizzle_blk(blockIdx.x);
    int b = blk >> 8;
    int t = blk & 255;
    int x0 = (t >> 4) * TILE;
    int y0 = (t & 15) * TILE;
    int tid = threadIdx.x;
    if (tid < W_) { wC[tid] = ci[tid]; wB[tid] = bi[tid]; wA[tid] = ai[tid]; bs[tid] = bias_i[tid]; }
    const float* xb = x + (size_t)b * LL;
    for (int idx = tid; idx < 18*18; idx += 256) {
        int dy = idx / 18, dx = idx % 18;
        int gx = (x0 + dy - 1) & 255;
        int gy = (y0 + dx - 1) & 255;
        tile[idx] = scale * xb[gx * L_ + gy];
    }
    __syncthreads();
    int dx = tid & 15, dy = tid >> 4;
    const float* c0 = &tile[dy * 18 + dx];
    float ctr = c0[19];
    float nb  = c0[1] + c0[37] + c0[18] + c0[20];
    float dg  = c0[0] + c0[2] + c0[36] + c0[38];
    floatx2 ctr2 = floatx2{ctr, ctr};
    floatx2 nb2  = floatx2{nb, nb};
    floatx2 dg2  = floatx2{dg, dg};
    unsigned od[16];
    #pragma unroll
    for (int o = 0; o < 16; ++o) {
        floatx2 wcv = *(const floatx2*)(&wC[2*o]);
        floatx2 wbv = *(const floatx2*)(&wB[2*o]);
        floatx2 wav = *(const floatx2*)(&wA[2*o]);
        floatx2 bsv = *(const floatx2*)(&bs[2*o]);
        floatx2 v = fma2(wcv, ctr2, fma2(wbv, nb2, fma2(wav, dg2, bsv)));
        od[o] = gelu2_pack(v);
    }
    unsigned* dst = (unsigned*)(hout + (((((size_t)b << 8) | (unsigned)(x0+dy)) << 8 | (unsigned)(y0+dx)) << 5));
    *(uintx4*)(dst)      = uintx4{od[0],  od[1],  od[2],  od[3]};
    *(uintx4*)(dst + 4)  = uintx4{od[4],  od[5],  od[6],  od[7]};
    *(uintx4*)(dst + 8)  = uintx4{od[8],  od[9],  od[10], od[11]};
    *(uintx4*)(dst + 12) = uintx4{od[12], od[13], od[14], od[15]};
}

// ---------------- fused middle-layer pair: site-major in/out, paired-row conv ----
// Position (r,c) r,c in 0..19  <->  global (x0+r-2, y0+c-2), 32ch bf16 @ PSTR=40.
// Layer A (mid k): 18x18 sites, taps = positions (i..i+2, j..j+2), out shifted to (i,j).
// Layer B (mid k+1): 16x16 sites, out to global.
// Staging: DMA, 5 granules of 16B per position (4 data + 1 pad, clamped src).
__global__ __launch_bounds__(256, 4) void kern_mid2(
        const unsigned short* __restrict__ hin,
        const float* __restrict__ wc1, const float* __restrict__ wb1,
        const float* __restrict__ wa1, const float* __restrict__ bias1,
        const float* __restrict__ wc2, const float* __restrict__ wb2,
        const float* __restrict__ wa2, const float* __restrict__ bias2,
        unsigned short* __restrict__ hout) {
    __shared__ unsigned short tile2[400 * PSTR];     // 32000 B

    const int tid = threadIdx.x;
    const int blk = swizzle_blk(blockIdx.x);
    const int b  = blk >> 8;
    const int t  = blk & 255;
    const int x0 = (t >> 4) * TILE;
    const int y0 = (t & 15) * TILE;

    const unsigned short* hb = hin + ((size_t)b << 21);

    // ---- stage: async DMA, 2000 granules of 16B; LDS offset = j*16 (linear) ----
    #pragma unroll
    for (int jj = 0; jj < 8; ++jj) {
        int j = tid + jj * 256;
        if (j < 2000) {
            int pos = (j * 3277) >> 14;     // j / 5
            int qtr = j - pos * 5;          // 0..4 (4 = pad granule)
            int qe  = qtr < 4 ? qtr : 3;    // clamp pad source in-bounds
            int r = (pos * 3277) >> 16;     // pos / 20
            int c = pos - r * 20;
            int gx = (x0 + r - 2) & 255;
            int gy = (y0 + c - 2) & 255;
            const unsigned short* src = hb + ((((unsigned)gx << 8) | (unsigned)gy) << 5) + qe*8;
            lds_dma16(src, tile2 + (size_t)j * 8);
        }
    }

    const int lane = tid & 63;
    const int wv   = tid >> 6;
    const int m    = lane & 15;
    const int q    = lane >> 4;

    shortx8 afrag[3][2];
    floatx4 bvv[2];
    build_afrag(wc1, wb1, wa1, bias1, m, q, afrag, bvv);

    __syncthreads();    // drains DMA (vmcnt) + weight loads

#define LDT(tr, off) (*(const shortx8*)(tile2 + (((tr)*20 + m + (off)))*PSTR + q*8))

    const int trow0 = wv * 4;
    shortx8 R0[3], R1[3], R2[3], R3[3], R4[3], R5[3];
    #pragma unroll
    for (int o = 0; o < 3; ++o) {
        R0[o] = LDT(trow0 + 0, o);
        R1[o] = LDT(trow0 + 1, o);
        R2[o] = LDT(trow0 + 2, o);
        R3[o] = LDT(trow0 + 3, o);
    }
    unsigned heldA[2][4];
    {
        floatx4 accA[2], accB[2];
        conv9x2(R0, R1, R2, R3, afrag, bvv, accA, accB);
        gelu_pack4(accA, heldA[0]);
        gelu_pack4(accB, heldA[1]);
    }
    #pragma unroll
    for (int o = 0; o < 3; ++o) {
        R4[o] = LDT(trow0 + 4, o);
        R5[o] = LDT(trow0 + 5, o);
    }
    {
        floatx4 accA[2], accB[2];
        conv9x2(R2, R3, R4, R5, afrag, bvv, accA, accB);
        unsigned dA[4], dB[4];
        gelu_pack4(accA, dA);
        gelu_pack4(accB, dB);
        // rows 4wv+2,4wv+3 cols 0..15: proven unread by any concurrent wave
        unsigned short* wpA = tile2 + ((trow0 + 2)*20 + m)*PSTR + q*4;
        *(uintx2*)(wpA)      = uintx2{dA[0], dA[1]};
        *(uintx2*)(wpA + 16) = uintx2{dA[2], dA[3]};
        unsigned short* wpB = tile2 + ((trow0 + 3)*20 + m)*PSTR + q*4;
        *(uintx2*)(wpB)      = uintx2{dB[0], dB[1]};
        *(uintx2*)(wpB + 16) = uintx2{dB[2], dB[3]};
    }

    int er0, ec0;
    if (wv == 0)      { er0 = 16; ec0 = m;  }
    else if (wv == 1) { er0 = 17; ec0 = m;  }
    else if (wv == 2) { er0 = m;  ec0 = 16; }
    else              { er0 = m;  ec0 = 17; }
    unsigned heldE[4];
    {
        shortx8 T[3][3];
        #pragma unroll
        for (int i = 0; i < 3; ++i)
          #pragma unroll
          for (int o = 0; o < 3; ++o)
            T[i][o] = *(const shortx8*)(tile2 + ((er0 + i)*20 + ec0 + o)*PSTR + q*8);
        floatx4 acc[2];
        conv9(T[0][0], T[0][1], T[0][2], T[1][0], T[1][1], T[1][2],
              T[2][0], T[2][1], T[2][2], afrag, bvv, acc);
        gelu_pack4(acc, heldE);
    }
    const int heldEoff = (er0*20 + ec0)*PSTR + q*4;

    unsigned heldC[4];
    int heldCoff = 0;
    if (wv == 2) {
        int sr = 16 + ((m >> 1) & 1);
        int sc = 16 + (m & 1);
        shortx8 T[3][3];
        #pragma unroll
        for (int i = 0; i < 3; ++i)
          #pragma unroll
          for (int o = 0; o < 3; ++o)
            T[i][o] = *(const shortx8*)(tile2 + ((sr + i)*20 + sc + o)*PSTR + q*8);
        floatx4 acc[2];
        conv9(T[0][0], T[0][1], T[0][2], T[1][0], T[1][1], T[1][2],
              T[2][0], T[2][1], T[2][2], afrag, bvv, acc);
        gelu_pack4(acc, heldC);
        heldCoff = (sr*20 + sc)*PSTR + q*4;
    }

    __syncthreads();   // all layer-A tap reads complete

    #pragma unroll
    for (int rr = 0; rr < 2; ++rr) {
        unsigned short* wp = tile2 + ((trow0 + rr)*20 + m)*PSTR + q*4;
        *(uintx2*)(wp)      = uintx2{heldA[rr][0], heldA[rr][1]};
        *(uintx2*)(wp + 16) = uintx2{heldA[rr][2], heldA[rr][3]};
    }
    {
        unsigned short* wp = tile2 + heldEoff;
        *(uintx2*)(wp)      = uintx2{heldE[0], heldE[1]};
        *(uintx2*)(wp + 16) = uintx2{heldE[2], heldE[3]};
    }
    if (wv == 2 && m < 4) {
        unsigned short* wp = tile2 + heldCoff;
        *(uintx2*)(wp)      = uintx2{heldC[0], heldC[1]};
        *(uintx2*)(wp + 16) = uintx2{heldC[2], heldC[3]};
    }

    build_afrag(wc2, wb2, wa2, bias2, m, q, afrag, bvv);

    __syncthreads();   // mid-k+1 field complete at positions (0..17)^2

    unsigned short* outb = hout + ((size_t)b << 21);
    #pragma unroll
    for (int o = 0; o < 3; ++o) {
        R0[o] = LDT(trow0 + 0, o);
        R1[o] = LDT(trow0 + 1, o);
        R2[o] = LDT(trow0 + 2, o);
        R3[o] = LDT(trow0 + 3, o);
    }
    {
        floatx4 accA[2], accB[2];
        conv9x2(R0, R1, R2, R3, afrag, bvv, accA, accB);
        unsigned dA[4], dB[4];
        gelu_pack4(accA, dA);
        gelu_pack4(accB, dB);
        unsigned short* dstA = outb + ((((unsigned)(x0 + trow0 + 0) << 8) | (unsigned)(y0 + m)) << 5) + q*4;
        *(uintx2*)(dstA)      = uintx2{dA[0], dA[1]};
        *(uintx2*)(dstA + 16) = uintx2{dA[2], dA[3]};
        unsigned short* dstB = outb + ((((unsigned)(x0 + trow0 + 1) << 8) | (unsigned)(y0 + m)) << 5) + q*4;
        *(uintx2*)(dstB)      = uintx2{dB[0], dB[1]};
        *(uintx2*)(dstB + 16) = uintx2{dB[2], dB[3]};
    }
    #pragma unroll
    for (int o = 0; o < 3; ++o) {
        R4[o] = LDT(trow0 + 4, o);
        R5[o] = LDT(trow0 + 5, o);
    }
    {
        floatx4 accA[2], accB[2];
        conv9x2(R2, R3, R4, R5, afrag, bvv, accA, accB);
        unsigned dA[4], dB[4];
        gelu_pack4(accA, dA);
        gelu_pack4(accB, dB);
        unsigned short* dstA = outb + ((((unsigned)(x0 + trow0 + 2) << 8) | (unsigned)(y0 + m)) << 5) + q*4;
        *(uintx2*)(dstA)      = uintx2{dA[0], dA[1]};
        *(uintx2*)(dstA + 16) = uintx2{dA[2], dA[3]};
        unsigned short* dstB = outb + ((((unsigned)(x0 + trow0 + 3) << 8) | (unsigned)(y0 + m)) << 5) + q*4;
        *(uintx2*)(dstB)      = uintx2{dB[0], dB[1]};
        *(uintx2*)(dstB + 16) = uintx2{dB[2], dB[3]};
    }
#undef LDT
}

// ---------------- last layer: 32 -> 1 channel via row-0 MFMA, antisym, row pairs ----------------
__global__ __launch_bounds__(256, 6) void kern_last(
        const unsigned short* __restrict__ hin,
        const float* __restrict__ co, const float* __restrict__ bo,
        const float* __restrict__ ao,
        float* __restrict__ out, int mode) {
    __shared__ unsigned short tile2[324 * PSTR];     // 25920 B
    const int tid = threadIdx.x;
    const int blk = swizzle_blk(blockIdx.x);
    const int b  = blk >> 8;
    const int t  = blk & 255;
    const int x0 = (t >> 4) * TILE;
    const int y0 = (t & 15) * TILE;

    const unsigned short* hb = hin + ((size_t)b << 21);
    // stage 18x18 positions (halo 1): 1620 DMA granules of 16B (5/pos, pad clamped)
    #pragma unroll
    for (int jj = 0; jj < 7; ++jj) {
        int j = tid + jj * 256;
        if (j < 1620) {
            int pos = (j * 3277) >> 14;     // j / 5
            int qtr = j - pos * 5;
            int qe  = qtr < 4 ? qtr : 3;
            int r = (pos * 3641) >> 16;     // pos / 18
            int c = pos - r * 18;
            int gx = (x0 + r - 1) & 255;
            int gy = (y0 + c - 1) & 255;
            const unsigned short* src = hb + ((((unsigned)gx << 8) | (unsigned)gy) << 5) + qe*8;
            lds_dma16(src, tile2 + (size_t)j * 8);
        }
    }

    const int lane = tid & 63;
    const int wv   = tid >> 6;
    const int m    = lane & 15;
    const int q    = lane >> 4;

    const float* wm[3] = { co, bo, ao };
    shortx8 afl[3];
    float z = (m == 0) ? 1.0f : 0.0f;
    #pragma unroll
    for (int f = 0; f < 3; ++f) {
        const float* row = wm[f] + q*8;
        floatx4 r0 = *(const floatx4*)(row);
        floatx4 r1 = *(const floatx4*)(row + 4);
        union { shortx8 s; unsigned u[4]; } w;
        w.u[0] = pack_bf2(r0.x * z, r0.y * z);
        w.u[1] = pack_bf2(r0.z * z, r0.w * z);
        w.u[2] = pack_bf2(r1.x * z, r1.y * z);
        w.u[3] = pack_bf2(r1.z * z, r1.w * z);
        afl[f] = w.s;
    }
    const floatx4 zc = {0.f, 0.f, 0.f, 0.f};

    __syncthreads();

#define LDT18(tr, off) (*(const shortx8*)(tile2 + (((tr)*18 + m + (off)))*PSTR + q*8))
    const int trow0 = wv * 4;
    shortx8 R0[3], R1[3], R2[3], R3[3], R4[3], R5[3];
    #pragma unroll
    for (int o = 0; o < 3; ++o) {
        R0[o] = LDT18(trow0 + 0, o);
        R1[o] = LDT18(trow0 + 1, o);
        R2[o] = LDT18(trow0 + 2, o);
        R3[o] = LDT18(trow0 + 3, o);
    }
    {
        floatx4 aA, aB;
        conv9x2_last(R0, R1, R2, R3, afl, zc, aA, aB);
        if (q == 0) {
            size_t o0 = (size_t)b * LL + (size_t)(x0 + trow0 + 0) * L_ + (y0 + m);
            size_t o1 = (size_t)b * LL + (size_t)(x0 + trow0 + 1) * L_ + (y0 + m);
            float v0 = 0.5f * aA[0];
            float v1 = 0.5f * aB[0];
            if (mode == 0) { out[o0] = v0;           out[o1] = v1;           }
            else           { out[o0] = out[o0] - v0; out[o1] = out[o1] - v1; }
        }
    }
    #pragma unroll
    for (int o = 0; o < 3; ++o) {
        R4[o] = LDT18(trow0 + 4, o);
        R5[o] = LDT18(trow0 + 5, o);
    }
    {
        floatx4 aA, aB;
        conv9x2_last(R2, R3, R4, R5, afl, zc, aA, aB);
        if (q == 0) {
            size_t o0 = (size_t)b * LL + (size_t)(x0 + trow0 + 2) * L_ + (y0 + m);
            size_t o1 = (size_t)b * LL + (size_t)(x0 + trow0 + 3) * L_ + (y0 + m);
            float v0 = 0.5f * aA[0];
            float v1 = 0.5f * aB[0];
            if (mode == 0) { out[o0] = v0;           out[o1] = v1;           }
            else           { out[o0] = out[o0] - v0; out[o1] = out[o1] - v1; }
        }
    }
#undef LDT18
}

extern "C" void kernel_launch(void* const* d_in, const int* in_sizes, int n_in,
                              void* d_out, int out_size, void* d_ws, size_t ws_size,
                              hipStream_t stream) {
    const float* x      = (const float*)d_in[0];
    const float* ai     = (const float*)d_in[1];
    const float* ao     = (const float*)d_in[2];
    const float* a      = (const float*)d_in[3];
    const float* bi     = (const float*)d_in[4];
    const float* bo     = (const float*)d_in[5];
    const float* b      = (const float*)d_in[6];
    const float* ci     = (const float*)d_in[7];
    const float* co     = (const float*)d_in[8];
    const float* c      = (const float*)d_in[9];
    const float* bias_i = (const float*)d_in[10];
    const float* bias   = (const float*)d_in[11];
    float* out = (float*)d_out;

    const size_t elems = (size_t)B_ * W_ * LL;
    unsigned short* hA = (unsigned short*)d_ws;
    unsigned short* hB = hA + elems;

    dim3 grid(B_ * 256), blk(256);
    const int WW = W_ * W_;
    for (int s = 0; s < 2; ++s) {
        float scale = s ? -1.0f : 1.0f;
        kern_first<<<grid, blk, 0, stream>>>(x, scale, ci, bi, ai, bias_i, hA);
        kern_mid2<<<grid, blk, 0, stream>>>(hA,
            c, b, a, bias,
            c + WW, b + WW, a + WW, bias + W_,
            hB);
        kern_mid2<<<grid, blk, 0, stream>>>(hB,
            c + 2*WW, b + 2*WW, a + 2*WW, bias + 2*W_,
            c + 3*WW, b + 3*WW, a + 3*WW, bias + 3*W_,
            hA);
        kern_last<<<grid, blk, 0, stream>>>(hA, co, bo, ao, out, s);
    }
}

// Round 13
// 706.525 us; speedup vs baseline: 1.0242x; 1.0242x over previous
//
#include <hip/hip_runtime.h>
#include <hip/hip_bf16.h>

#define B_ 32
#define L_ 256
#define W_ 32
#define TILE 16
#define PSTR 40          // shorts per (row,col) position: 80B = 5*16B, b128-aligned
#define LL (L_*L_)
#define ELEMS ((size_t)B_ * W_ * LL)

typedef float    floatx4 __attribute__((ext_vector_type(4)));
typedef float    floatx2 __attribute__((ext_vector_type(2)));
typedef short    shortx8 __attribute__((ext_vector_type(8)));
typedef unsigned uintx2  __attribute__((ext_vector_type(2)));
typedef unsigned uintx4  __attribute__((ext_vector_type(4)));

typedef const __attribute__((address_space(1))) unsigned guint_t;
typedef __attribute__((address_space(3))) unsigned luint_t;

// async global->LDS DMA, 16B per lane; LDS image linear in granule index.
// NOTE (r10 lesson): EXEC mask must be a contiguous prefix of the wave.
__device__ __forceinline__ void lds_dma16(const unsigned short* src, unsigned short* dst) {
    __builtin_amdgcn_global_load_lds((guint_t*)src, (luint_t*)dst, 16, 0, 0);
}

__device__ __forceinline__ floatx2 fma2(floatx2 a, floatx2 b, floatx2 c) {
#if __has_builtin(__builtin_elementwise_fma)
    return __builtin_elementwise_fma(a, b, c);
#else
    return floatx2{fmaf(a.x, b.x, c.x), fmaf(a.y, b.y, c.y)};
#endif
}

#if __has_builtin(__builtin_amdgcn_cvt_pk_bf16_f32)
__device__ __forceinline__ unsigned pack_bf2(float a, float b) {
    auto v = __builtin_amdgcn_cvt_pk_bf16_f32(a, b);
    return __builtin_bit_cast(unsigned, v);
}
#else
__device__ __forceinline__ unsigned pack_bf2(float a, float b) {
    unsigned ua = __float_as_uint(a);
    unsigned ub = __float_as_uint(b);
    ua += 0x7fffu + ((ua >> 16) & 1u);
    ub += 0x7fffu + ((ub >> 16) & 1u);
    return (ua >> 16) | (ub & 0xffff0000u);
}
#endif

// ---- scalar fast GELU (round-1-proven arithmetic, used in kern_front) ----
__device__ __forceinline__ float gelu_fast(float x) {
    float x2 = x * x;
    float inner = fmaf(0.044715f * x2, x, x);
    float e = __builtin_amdgcn_exp2f(inner * -2.3022082299446597f);
    return x * __builtin_amdgcn_rcpf(1.0f + e);
}

// ---- packed GELU pair (round-11-proven, used in kern_mid2/kern_last) ----
__device__ __forceinline__ unsigned gelu2_pack(floatx2 x) {
    floatx2 x2    = x * x;
    floatx2 t     = x2 * 0.044715f;
    floatx2 inner = fma2(t, x, x);
    floatx2 z     = inner * -2.3022082299446597f;
    float e0 = __builtin_amdgcn_exp2f(z.x);
    float e1 = __builtin_amdgcn_exp2f(z.y);
    float r0 = __builtin_amdgcn_rcpf(1.0f + e0);
    float r1 = __builtin_amdgcn_rcpf(1.0f + e1);
    floatx2 g = x * floatx2{r0, r1};
    return pack_bf2(g.x, g.y);
}

__device__ __forceinline__ int swizzle_blk(int p) {
    return (p & 7) * 1024 + (p >> 3);
}

// ======================= round-1-style helpers (kern_front only) =======================
// 9-tap dual-half MFMA conv, accumulator initialized from bv arrays (round-1 text).
__device__ __forceinline__ void conv9_v1(
        const shortx8& t00, const shortx8& t01, const shortx8& t02,
        const shortx8& t10, const shortx8& t11, const shortx8& t12,
        const shortx8& t20, const shortx8& t21, const shortx8& t22,
        const shortx8 af[3][2], const float bv[2][4], floatx4 acc[2]) {
    #pragma unroll
    for (int h = 0; h < 2; ++h) {
        acc[h] = floatx4{bv[h][0], bv[h][1], bv[h][2], bv[h][3]};
        acc[h] = __builtin_amdgcn_mfma_f32_16x16x32_bf16(af[0][h], t11, acc[h], 0, 0, 0);
        acc[h] = __builtin_amdgcn_mfma_f32_16x16x32_bf16(af[1][h], t01, acc[h], 0, 0, 0);
        acc[h] = __builtin_amdgcn_mfma_f32_16x16x32_bf16(af[1][h], t21, acc[h], 0, 0, 0);
        acc[h] = __builtin_amdgcn_mfma_f32_16x16x32_bf16(af[1][h], t10, acc[h], 0, 0, 0);
        acc[h] = __builtin_amdgcn_mfma_f32_16x16x32_bf16(af[1][h], t12, acc[h], 0, 0, 0);
        acc[h] = __builtin_amdgcn_mfma_f32_16x16x32_bf16(af[2][h], t00, acc[h], 0, 0, 0);
        acc[h] = __builtin_amdgcn_mfma_f32_16x16x32_bf16(af[2][h], t02, acc[h], 0, 0, 0);
        acc[h] = __builtin_amdgcn_mfma_f32_16x16x32_bf16(af[2][h], t20, acc[h], 0, 0, 0);
        acc[h] = __builtin_amdgcn_mfma_f32_16x16x32_bf16(af[2][h], t22, acc[h], 0, 0, 0);
    }
}

__device__ __forceinline__ void gelu_pack4_v1(const floatx4 acc[2], unsigned d[4]) {
    d[0] = pack_bf2(gelu_fast(acc[0][0]), gelu_fast(acc[0][1]));
    d[1] = pack_bf2(gelu_fast(acc[0][2]), gelu_fast(acc[0][3]));
    d[2] = pack_bf2(gelu_fast(acc[1][0]), gelu_fast(acc[1][1]));
    d[3] = pack_bf2(gelu_fast(acc[1][2]), gelu_fast(acc[1][3]));
}

__device__ __forceinline__ void build_afrag_v1(
        const float* wc, const float* wb, const float* wa, const float* bias,
        int m, int q, shortx8 af[3][2], float bv[2][4]) {
    const float* wm[3] = { wc, wb, wa };
    #pragma unroll
    for (int f = 0; f < 3; ++f)
      #pragma unroll
      for (int h = 0; h < 2; ++h) {
        const float* row = wm[f] + (h*16 + m) * W_ + q*8;
        floatx4 r0 = *(const floatx4*)(row);
        floatx4 r1 = *(const floatx4*)(row + 4);
        union { shortx8 s; unsigned u[4]; } w;
        w.u[0] = pack_bf2(r0.x, r0.y);
        w.u[1] = pack_bf2(r0.z, r0.w);
        w.u[2] = pack_bf2(r1.x, r1.y);
        w.u[3] = pack_bf2(r1.z, r1.w);
        af[f][h] = w.s;
      }
    #pragma unroll
    for (int h = 0; h < 2; ++h)
      #pragma unroll
      for (int r = 0; r < 4; ++r)
        bv[h][r] = bias[h*16 + q*4 + r];
}

// ======================= round-11-style helpers (mid2/last) =======================
// 9-tap dual-half MFMA conv; bias enters as the C operand of the FIRST mfma.
__device__ __forceinline__ void conv9(
        const shortx8& t00, const shortx8& t01, const shortx8& t02,
        const shortx8& t10, const shortx8& t11, const shortx8& t12,
        const shortx8& t20, const shortx8& t21, const shortx8& t22,
        const shortx8 af[3][2], const floatx4 bvv[2], floatx4 acc[2]) {
    #pragma unroll
    for (int h = 0; h < 2; ++h) {
        acc[h] = __builtin_amdgcn_mfma_f32_16x16x32_bf16(af[0][h], t11, bvv[h], 0, 0, 0);
        acc[h] = __builtin_amdgcn_mfma_f32_16x16x32_bf16(af[1][h], t01, acc[h], 0, 0, 0);
        acc[h] = __builtin_amdgcn_mfma_f32_16x16x32_bf16(af[1][h], t21, acc[h], 0, 0, 0);
        acc[h] = __builtin_amdgcn_mfma_f32_16x16x32_bf16(af[1][h], t10, acc[h], 0, 0, 0);
        acc[h] = __builtin_amdgcn_mfma_f32_16x16x32_bf16(af[1][h], t12, acc[h], 0, 0, 0);
        acc[h] = __builtin_amdgcn_mfma_f32_16x16x32_bf16(af[2][h], t00, acc[h], 0, 0, 0);
        acc[h] = __builtin_amdgcn_mfma_f32_16x16x32_bf16(af[2][h], t02, acc[h], 0, 0, 0);
        acc[h] = __builtin_amdgcn_mfma_f32_16x16x32_bf16(af[2][h], t20, acc[h], 0, 0, 0);
        acc[h] = __builtin_amdgcn_mfma_f32_16x16x32_bf16(af[2][h], t22, acc[h], 0, 0, 0);
    }
}

// Dual-site conv: per-site MFMA order identical to conv9; bias folded into first mfma.
__device__ __forceinline__ void conv9x2(
        const shortx8 r0[3], const shortx8 r1[3],
        const shortx8 r2[3], const shortx8 r3[3],
        const shortx8 af[3][2], const floatx4 bvv[2],
        floatx4 accA[2], floatx4 accB[2]) {
    const shortx8* ra[3] = { r0, r1, r2 };
    const shortx8* rb[3] = { r1, r2, r3 };
    const int F[9] = {0,1,1,1,1,2,2,2,2};
    const int R[9] = {1,0,2,1,1,0,0,2,2};
    const int C[9] = {1,1,1,0,2,0,2,0,2};
    #pragma unroll
    for (int k = 0; k < 9; ++k)
      #pragma unroll
      for (int h = 0; h < 2; ++h) {
        accA[h] = __builtin_amdgcn_mfma_f32_16x16x32_bf16(af[F[k]][h], ra[R[k]][C[k]],
                      (k == 0) ? bvv[h] : accA[h], 0, 0, 0);
        accB[h] = __builtin_amdgcn_mfma_f32_16x16x32_bf16(af[F[k]][h], rb[R[k]][C[k]],
                      (k == 0) ? bvv[h] : accB[h], 0, 0, 0);
      }
}

// Dual-site conv for the last layer (single half, zero C), same op table.
__device__ __forceinline__ void conv9x2_last(
        const shortx8 r0[3], const shortx8 r1[3],
        const shortx8 r2[3], const shortx8 r3[3],
        const shortx8 afl[3], const floatx4& zc, floatx4& accA, floatx4& accB) {
    const shortx8* ra[3] = { r0, r1, r2 };
    const shortx8* rb[3] = { r1, r2, r3 };
    const int F[9] = {0,1,1,1,1,2,2,2,2};
    const int R[9] = {1,0,2,1,1,0,0,2,2};
    const int C[9] = {1,1,1,0,2,0,2,0,2};
    #pragma unroll
    for (int k = 0; k < 9; ++k) {
        accA = __builtin_amdgcn_mfma_f32_16x16x32_bf16(afl[F[k]], ra[R[k]][C[k]],
                   (k == 0) ? zc : accA, 0, 0, 0);
        accB = __builtin_amdgcn_mfma_f32_16x16x32_bf16(afl[F[k]], rb[R[k]][C[k]],
                   (k == 0) ? zc : accB, 0, 0, 0);
    }
}

__device__ __forceinline__ void gelu_pack4(const floatx4 acc[2], unsigned d[4]) {
    d[0] = gelu2_pack(floatx2{acc[0][0], acc[0][1]});
    d[1] = gelu2_pack(floatx2{acc[0][2], acc[0][3]});
    d[2] = gelu2_pack(floatx2{acc[1][0], acc[1][1]});
    d[3] = gelu2_pack(floatx2{acc[1][2], acc[1][3]});
}

__device__ __forceinline__ void build_afrag(
        const float* wc, const float* wb, const float* wa, const float* bias,
        int m, int q, shortx8 af[3][2], floatx4 bvv[2]) {
    const float* wm[3] = { wc, wb, wa };
    #pragma unroll
    for (int f = 0; f < 3; ++f)
      #pragma unroll
      for (int h = 0; h < 2; ++h) {
        const float* row = wm[f] + (h*16 + m) * W_ + q*8;
        floatx4 r0 = *(const floatx4*)(row);
        floatx4 r1 = *(const floatx4*)(row + 4);
        union { shortx8 s; unsigned u[4]; } w;
        w.u[0] = pack_bf2(r0.x, r0.y);
        w.u[1] = pack_bf2(r0.z, r0.w);
        w.u[2] = pack_bf2(r1.x, r1.y);
        w.u[3] = pack_bf2(r1.z, r1.w);
        af[f][h] = w.s;
      }
    #pragma unroll
    for (int h = 0; h < 2; ++h)
        bvv[h] = *(const floatx4*)(bias + h*16 + q*4);
}

// ---------------- front: first layer (1->32, VALU, in-LDS) + mid0 + mid1 ----------------
// ROUND-1 TEXT (passed at 1189 µs), sign via scale argument (proven in kern_first).
// xs (rr,cc) rr,cc in 0..21 <-> global (x0+rr-3, y0+cc-3)  [f32, LDS, stride 23]
// tile2 pos (r,c) r,c in 0..19 <-> global (x0+r-2, y0+c-2), first-layer output (32ch bf16)
// mid0: 18x18 sites (shifted in place); mid1: 16x16 sites -> global hout.
__global__ __launch_bounds__(256, 4) void kern_front(
        const float* __restrict__ x, float scale,
        const float* __restrict__ ci, const float* __restrict__ bi,
        const float* __restrict__ ai, const float* __restrict__ bias_i,
        const float* __restrict__ wc1, const float* __restrict__ wb1,
        const float* __restrict__ wa1, const float* __restrict__ bias1,
        const float* __restrict__ wc2, const float* __restrict__ wb2,
        const float* __restrict__ wa2, const float* __restrict__ bias2,
        unsigned short* __restrict__ hout) {
    __shared__ unsigned short tile2[400 * PSTR];     // 32000 B
    __shared__ float xs[22 * 23];                    // 2024 B
    __shared__ float wC[W_], wB[W_], wA[W_], bs[W_];

    const int tid = threadIdx.x;
    const int blk = swizzle_blk(blockIdx.x);
    const int b  = blk >> 8;
    const int t  = blk & 255;
    const int x0 = (t >> 4) * TILE;
    const int y0 = (t & 15) * TILE;

    if (tid < W_) { wC[tid] = ci[tid]; wB[tid] = bi[tid]; wA[tid] = ai[tid]; bs[tid] = bias_i[tid]; }

    const float* xb = x + (size_t)b * LL;
    #pragma unroll
    for (int ss = 0; ss < 2; ++ss) {
        int idx = tid + ss * 256;
        if (idx < 484) {
            int r = (idx * 2979) >> 16;      // idx / 22
            int c = idx - r * 22;
            int gx = (x0 + r - 3) & 255;
            int gy = (y0 + c - 3) & 255;
            xs[r * 23 + c] = scale * xb[gx * L_ + gy];
        }
    }
    __syncthreads();

    // ---- first layer: 400 sites, 32 channels each, pure VALU (round-1 scalar form) ----
    #pragma unroll
    for (int ss = 0; ss < 2; ++ss) {
        int idx = tid + ss * 256;
        if (idx < 400) {
            int i = (idx * 3277) >> 16;      // idx / 20
            int j = idx - i * 20;
            const float* p0 = &xs[i * 23 + j];
            float ctr = p0[24];
            float nb  = p0[1] + p0[47] + p0[23] + p0[25];
            float dg  = p0[0] + p0[2] + p0[46] + p0[48];
            unsigned od[16];
            #pragma unroll
            for (int o = 0; o < 16; ++o) {
                float v0 = gelu_fast(wC[2*o]*ctr + wB[2*o]*nb + wA[2*o]*dg + bs[2*o]);
                float v1 = gelu_fast(wC[2*o+1]*ctr + wB[2*o+1]*nb + wA[2*o+1]*dg + bs[2*o+1]);
                od[o] = pack_bf2(v0, v1);
            }
            unsigned* dst = (unsigned*)(tile2 + idx * PSTR);
            *(uintx4*)(dst)      = uintx4{od[0],  od[1],  od[2],  od[3]};
            *(uintx4*)(dst + 4)  = uintx4{od[4],  od[5],  od[6],  od[7]};
            *(uintx4*)(dst + 8)  = uintx4{od[8],  od[9],  od[10], od[11]};
            *(uintx4*)(dst + 12) = uintx4{od[12], od[13], od[14], od[15]};
        }
    }

    const int lane = tid & 63;
    const int wv   = tid >> 6;
    const int m    = lane & 15;
    const int q    = lane >> 4;

    shortx8 afrag[3][2];
    float bv[2][4];
    build_afrag_v1(wc1, wb1, wa1, bias1, m, q, afrag, bv);

    __syncthreads();    // first-layer field complete

#define LDT(tr, off) (*(const shortx8*)(tile2 + (((tr)*20 + m + (off)))*PSTR + q*8))

    // ---- mid0 main: wave wv -> site rows 4wv..4wv+3, cols m (0..15), sliding ring ----
    const int trow0 = wv * 4;
    shortx8 W[3][3];
    #pragma unroll
    for (int i = 0; i < 3; ++i) {
        W[i][0] = LDT(trow0 + i, 0);
        W[i][1] = LDT(trow0 + i, 1);
        W[i][2] = LDT(trow0 + i, 2);
    }
    unsigned heldA[2][4];
    #pragma unroll
    for (int rr = 0; rr < 4; ++rr) {
        const int top = rr % 3, mid = (rr + 1) % 3, bot = (rr + 2) % 3;
        floatx4 acc[2];
        conv9_v1(W[top][0], W[top][1], W[top][2],
                 W[mid][0], W[mid][1], W[mid][2],
                 W[bot][0], W[bot][1], W[bot][2], afrag, bv, acc);
        unsigned d[4];
        gelu_pack4_v1(acc, d);
        if (rr < 2) {
            heldA[rr][0] = d[0]; heldA[rr][1] = d[1];
            heldA[rr][2] = d[2]; heldA[rr][3] = d[3];
        } else {
            // rows 4wv+2,4wv+3 cols 0..15: proven unread by any concurrent wave
            unsigned short* wp = tile2 + ((trow0 + rr)*20 + m)*PSTR + q*4;
            *(uintx2*)(wp)      = uintx2{d[0], d[1]};
            *(uintx2*)(wp + 16) = uintx2{d[2], d[3]};
        }
        if (rr < 3) {
            W[top][0] = LDT(trow0 + rr + 3, 0);
            W[top][1] = LDT(trow0 + rr + 3, 1);
            W[top][2] = LDT(trow0 + rr + 3, 2);
        }
    }

    // ---- mid0 edges: rows 16,17 (waves 0,1) / cols 16,17 (waves 2,3) + corners (wave 2) ----
    int er0, ec0;
    if (wv == 0)      { er0 = 16; ec0 = m;  }
    else if (wv == 1) { er0 = 17; ec0 = m;  }
    else if (wv == 2) { er0 = m;  ec0 = 16; }
    else              { er0 = m;  ec0 = 17; }
    unsigned heldE[4];
    {
        shortx8 T[3][3];
        #pragma unroll
        for (int i = 0; i < 3; ++i)
          #pragma unroll
          for (int o = 0; o < 3; ++o)
            T[i][o] = *(const shortx8*)(tile2 + ((er0 + i)*20 + ec0 + o)*PSTR + q*8);
        floatx4 acc[2];
        conv9_v1(T[0][0], T[0][1], T[0][2], T[1][0], T[1][1], T[1][2],
                 T[2][0], T[2][1], T[2][2], afrag, bv, acc);
        gelu_pack4_v1(acc, heldE);
    }
    const int heldEoff = (er0*20 + ec0)*PSTR + q*4;

    unsigned heldC[4];
    int heldCoff = 0;
    if (wv == 2) {
        int sr = 16 + ((m >> 1) & 1);
        int sc = 16 + (m & 1);
        shortx8 T[3][3];
        #pragma unroll
        for (int i = 0; i < 3; ++i)
          #pragma unroll
          for (int o = 0; o < 3; ++o)
            T[i][o] = *(const shortx8*)(tile2 + ((sr + i)*20 + sc + o)*PSTR + q*8);
        floatx4 acc[2];
        conv9_v1(T[0][0], T[0][1], T[0][2], T[1][0], T[1][1], T[1][2],
                 T[2][0], T[2][1], T[2][2], afrag, bv, acc);
        gelu_pack4_v1(acc, heldC);
        heldCoff = (sr*20 + sc)*PSTR + q*4;
    }

    __syncthreads();   // all mid0 tap reads complete

    #pragma unroll
    for (int rr = 0; rr < 2; ++rr) {
        unsigned short* wp = tile2 + ((trow0 + rr)*20 + m)*PSTR + q*4;
        *(uintx2*)(wp)      = uintx2{heldA[rr][0], heldA[rr][1]};
        *(uintx2*)(wp + 16) = uintx2{heldA[rr][2], heldA[rr][3]};
    }
    {
        unsigned short* wp = tile2 + heldEoff;
        *(uintx2*)(wp)      = uintx2{heldE[0], heldE[1]};
        *(uintx2*)(wp + 16) = uintx2{heldE[2], heldE[3]};
    }
    if (wv == 2 && m < 4) {
        unsigned short* wp = tile2 + heldCoff;
        *(uintx2*)(wp)      = uintx2{heldC[0], heldC[1]};
        *(uintx2*)(wp + 16) = uintx2{heldC[2], heldC[3]};
    }

    build_afrag_v1(wc2, wb2, wa2, bias2, m, q, afrag, bv);

    __syncthreads();   // mid0 field complete at positions (0..17)^2

    // ---- mid1: wave wv -> site rows 4wv..4wv+3, cols m; out to global; sliding ring ----
    unsigned short* outb = hout + ((size_t)b << 21);
    #pragma unroll
    for (int i = 0; i < 3; ++i) {
        W[i][0] = LDT(trow0 + i, 0);
        W[i][1] = LDT(trow0 + i, 1);
        W[i][2] = LDT(trow0 + i, 2);
    }
    #pragma unroll
    for (int rr = 0; rr < 4; ++rr) {
        const int top = rr % 3, mid = (rr + 1) % 3, bot = (rr + 2) % 3;
        floatx4 acc[2];
        conv9_v1(W[top][0], W[top][1], W[top][2],
                 W[mid][0], W[mid][1], W[mid][2],
                 W[bot][0], W[bot][1], W[bot][2], afrag, bv, acc);
        unsigned d[4];
        gelu_pack4_v1(acc, d);
        unsigned short* dst = outb + ((((unsigned)(x0 + trow0 + rr) << 8) | (unsigned)(y0 + m)) << 5) + q*4;
        *(uintx2*)(dst)      = uintx2{d[0], d[1]};
        *(uintx2*)(dst + 16) = uintx2{d[2], d[3]};
        if (rr < 3) {
            W[top][0] = LDT(trow0 + rr + 3, 0);
            W[top][1] = LDT(trow0 + rr + 3, 1);
            W[top][2] = LDT(trow0 + rr + 3, 2);
        }
    }
#undef LDT
}

// ---------------- fused middle-layer pair (mid2+mid3): unchanged from round 11 ----------------
__global__ __launch_bounds__(256, 4) void kern_mid2(
        const unsigned short* __restrict__ hin,
        const float* __restrict__ wc1, const float* __restrict__ wb1,
        const float* __restrict__ wa1, const float* __restrict__ bias1,
        const float* __restrict__ wc2, const float* __restrict__ wb2,
        const float* __restrict__ wa2, const float* __restrict__ bias2,
        unsigned short* __restrict__ hout) {
    __shared__ unsigned short tile2[400 * PSTR];     // 32000 B

    const int tid = threadIdx.x;
    const int blk = swizzle_blk(blockIdx.x);
    const int b  = blk >> 8;
    const int t  = blk & 255;
    const int x0 = (t >> 4) * TILE;
    const int y0 = (t & 15) * TILE;

    const unsigned short* hb = hin + ((size_t)b << 21);

    // ---- stage: async DMA, 2000 granules of 16B; LDS offset = j*16 (linear) ----
    #pragma unroll
    for (int jj = 0; jj < 8; ++jj) {
        int j = tid + jj * 256;
        if (j < 2000) {
            int pos = (j * 3277) >> 14;     // j / 5
            int qtr = j - pos * 5;          // 0..4 (4 = pad granule)
            int qe  = qtr < 4 ? qtr : 3;    // clamp pad source in-bounds
            int r = (pos * 3277) >> 16;     // pos / 20
            int c = pos - r * 20;
            int gx = (x0 + r - 2) & 255;
            int gy = (y0 + c - 2) & 255;
            const unsigned short* src = hb + ((((unsigned)gx << 8) | (unsigned)gy) << 5) + qe*8;
            lds_dma16(src, tile2 + (size_t)j * 8);
        }
    }

    const int lane = tid & 63;
    const int wv   = tid >> 6;
    const int m    = lane & 15;
    const int q    = lane >> 4;

    shortx8 afrag[3][2];
    floatx4 bvv[2];
    build_afrag(wc1, wb1, wa1, bias1, m, q, afrag, bvv);

    __syncthreads();    // drains DMA (vmcnt) + weight loads

#define LDT(tr, off) (*(const shortx8*)(tile2 + (((tr)*20 + m + (off)))*PSTR + q*8))

    const int trow0 = wv * 4;
    shortx8 R0[3], R1[3], R2[3], R3[3], R4[3], R5[3];
    #pragma unroll
    for (int o = 0; o < 3; ++o) {
        R0[o] = LDT(trow0 + 0, o);
        R1[o] = LDT(trow0 + 1, o);
        R2[o] = LDT(trow0 + 2, o);
        R3[o] = LDT(trow0 + 3, o);
    }
    unsigned heldA[2][4];
    {
        floatx4 accA[2], accB[2];
        conv9x2(R0, R1, R2, R3, afrag, bvv, accA, accB);
        gelu_pack4(accA, heldA[0]);
        gelu_pack4(accB, heldA[1]);
    }
    #pragma unroll
    for (int o = 0; o < 3; ++o) {
        R4[o] = LDT(trow0 + 4, o);
        R5[o] = LDT(trow0 + 5, o);
    }
    {
        floatx4 accA[2], accB[2];
        conv9x2(R2, R3, R4, R5, afrag, bvv, accA, accB);
        unsigned dA[4], dB[4];
        gelu_pack4(accA, dA);
        gelu_pack4(accB, dB);
        // rows 4wv+2,4wv+3 cols 0..15: proven unread by any concurrent wave
        unsigned short* wpA = tile2 + ((trow0 + 2)*20 + m)*PSTR + q*4;
        *(uintx2*)(wpA)      = uintx2{dA[0], dA[1]};
        *(uintx2*)(wpA + 16) = uintx2{dA[2], dA[3]};
        unsigned short* wpB = tile2 + ((trow0 + 3)*20 + m)*PSTR + q*4;
        *(uintx2*)(wpB)      = uintx2{dB[0], dB[1]};
        *(uintx2*)(wpB + 16) = uintx2{dB[2], dB[3]};
    }

    int er0, ec0;
    if (wv == 0)      { er0 = 16; ec0 = m;  }
    else if (wv == 1) { er0 = 17; ec0 = m;  }
    else if (wv == 2) { er0 = m;  ec0 = 16; }
    else              { er0 = m;  ec0 = 17; }
    unsigned heldE[4];
    {
        shortx8 T[3][3];
        #pragma unroll
        for (int i = 0; i < 3; ++i)
          #pragma unroll
          for (int o = 0; o < 3; ++o)
            T[i][o] = *(const shortx8*)(tile2 + ((er0 + i)*20 + ec0 + o)*PSTR + q*8);
        floatx4 acc[2];
        conv9(T[0][0], T[0][1], T[0][2], T[1][0], T[1][1], T[1][2],
              T[2][0], T[2][1], T[2][2], afrag, bvv, acc);
        gelu_pack4(acc, heldE);
    }
    const int heldEoff = (er0*20 + ec0)*PSTR + q*4;

    unsigned heldC[4];
    int heldCoff = 0;
    if (wv == 2) {
        int sr = 16 + ((m >> 1) & 1);
        int sc = 16 + (m & 1);
        shortx8 T[3][3];
        #pragma unroll
        for (int i = 0; i < 3; ++i)
          #pragma unroll
          for (int o = 0; o < 3; ++o)
            T[i][o] = *(const shortx8*)(tile2 + ((sr + i)*20 + sc + o)*PSTR + q*8);
        floatx4 acc[2];
        conv9(T[0][0], T[0][1], T[0][2], T[1][0], T[1][1], T[1][2],
              T[2][0], T[2][1], T[2][2], afrag, bvv, acc);
        gelu_pack4(acc, heldC);
        heldCoff = (sr*20 + sc)*PSTR + q*4;
    }

    __syncthreads();   // all layer-A tap reads complete

    #pragma unroll
    for (int rr = 0; rr < 2; ++rr) {
        unsigned short* wp = tile2 + ((trow0 + rr)*20 + m)*PSTR + q*4;
        *(uintx2*)(wp)      = uintx2{heldA[rr][0], heldA[rr][1]};
        *(uintx2*)(wp + 16) = uintx2{heldA[rr][2], heldA[rr][3]};
    }
    {
        unsigned short* wp = tile2 + heldEoff;
        *(uintx2*)(wp)      = uintx2{heldE[0], heldE[1]};
        *(uintx2*)(wp + 16) = uintx2{heldE[2], heldE[3]};
    }
    if (wv == 2 && m < 4) {
        unsigned short* wp = tile2 + heldCoff;
        *(uintx2*)(wp)      = uintx2{heldC[0], heldC[1]};
        *(uintx2*)(wp + 16) = uintx2{heldC[2], heldC[3]};
    }

    build_afrag(wc2, wb2, wa2, bias2, m, q, afrag, bvv);

    __syncthreads();   // mid-k+1 field complete at positions (0..17)^2

    unsigned short* outb = hout + ((size_t)b << 21);
    #pragma unroll
    for (int o = 0; o < 3; ++o) {
        R0[o] = LDT(trow0 + 0, o);
        R1[o] = LDT(trow0 + 1, o);
        R2[o] = LDT(trow0 + 2, o);
        R3[o] = LDT(trow0 + 3, o);
    }
    {
        floatx4 accA[2], accB[2];
        conv9x2(R0, R1, R2, R3, afrag, bvv, accA, accB);
        unsigned dA[4], dB[4];
        gelu_pack4(accA, dA);
        gelu_pack4(accB, dB);
        unsigned short* dstA = outb + ((((unsigned)(x0 + trow0 + 0) << 8) | (unsigned)(y0 + m)) << 5) + q*4;
        *(uintx2*)(dstA)      = uintx2{dA[0], dA[1]};
        *(uintx2*)(dstA + 16) = uintx2{dA[2], dA[3]};
        unsigned short* dstB = outb + ((((unsigned)(x0 + trow0 + 1) << 8) | (unsigned)(y0 + m)) << 5) + q*4;
        *(uintx2*)(dstB)      = uintx2{dB[0], dB[1]};
        *(uintx2*)(dstB + 16) = uintx2{dB[2], dB[3]};
    }
    #pragma unroll
    for (int o = 0; o < 3; ++o) {
        R4[o] = LDT(trow0 + 4, o);
        R5[o] = LDT(trow0 + 5, o);
    }
    {
        floatx4 accA[2], accB[2];
        conv9x2(R2, R3, R4, R5, afrag, bvv, accA, accB);
        unsigned dA[4], dB[4];
        gelu_pack4(accA, dA);
        gelu_pack4(accB, dB);
        unsigned short* dstA = outb + ((((unsigned)(x0 + trow0 + 2) << 8) | (unsigned)(y0 + m)) << 5) + q*4;
        *(uintx2*)(dstA)      = uintx2{dA[0], dA[1]};
        *(uintx2*)(dstA + 16) = uintx2{dA[2], dA[3]};
        unsigned short* dstB = outb + ((((unsigned)(x0 + trow0 + 3) << 8) | (unsigned)(y0 + m)) << 5) + q*4;
        *(uintx2*)(dstB)      = uintx2{dB[0], dB[1]};
        *(uintx2*)(dstB + 16) = uintx2{dB[2], dB[3]};
    }
#undef LDT
}

// ---------------- last layer: unchanged from round 11 ----------------
__global__ __launch_bounds__(256, 6) void kern_last(
        const unsigned short* __restrict__ hin,
        const float* __restrict__ co, const float* __restrict__ bo,
        const float* __restrict__ ao,
        float* __restrict__ out, int mode) {
    __shared__ unsigned short tile2[324 * PSTR];     // 25920 B
    const int tid = threadIdx.x;
    const int blk = swizzle_blk(blockIdx.x);
    const int b  = blk >> 8;
    const int t  = blk & 255;
    const int x0 = (t >> 4) * TILE;
    const int y0 = (t & 15) * TILE;

    const unsigned short* hb = hin + ((size_t)b << 21);
    // stage 18x18 positions (halo 1): 1620 DMA granules of 16B (5/pos, pad clamped)
    #pragma unroll
    for (int jj = 0; jj < 7; ++jj) {
        int j = tid + jj * 256;
        if (j < 1620) {
            int pos = (j * 3277) >> 14;     // j / 5
            int qtr = j - pos * 5;
            int qe  = qtr < 4 ? qtr : 3;
            int r = (pos * 3641) >> 16;     // pos / 18
            int c = pos - r * 18;
            int gx = (x0 + r - 1) & 255;
            int gy = (y0 + c - 1) & 255;
            const unsigned short* src = hb + ((((unsigned)gx << 8) | (unsigned)gy) << 5) + qe*8;
            lds_dma16(src, tile2 + (size_t)j * 8);
        }
    }

    const int lane = tid & 63;
    const int wv   = tid >> 6;
    const int m    = lane & 15;
    const int q    = lane >> 4;

    const float* wm[3] = { co, bo, ao };
    shortx8 afl[3];
    float z = (m == 0) ? 1.0f : 0.0f;
    #pragma unroll
    for (int f = 0; f < 3; ++f) {
        const float* row = wm[f] + q*8;
        floatx4 r0 = *(const floatx4*)(row);
        floatx4 r1 = *(const floatx4*)(row + 4);
        union { shortx8 s; unsigned u[4]; } w;
        w.u[0] = pack_bf2(r0.x * z, r0.y * z);
        w.u[1] = pack_bf2(r0.z * z, r0.w * z);
        w.u[2] = pack_bf2(r1.x * z, r1.y * z);
        w.u[3] = pack_bf2(r1.z * z, r1.w * z);
        afl[f] = w.s;
    }
    const floatx4 zc = {0.f, 0.f, 0.f, 0.f};

    __syncthreads();

#define LDT18(tr, off) (*(const shortx8*)(tile2 + (((tr)*18 + m + (off)))*PSTR + q*8))
    const int trow0 = wv * 4;
    shortx8 R0[3], R1[3], R2[3], R3[3], R4[3], R5[3];
    #pragma unroll
    for (int o = 0; o < 3; ++o) {
        R0[o] = LDT18(trow0 + 0, o);
        R1[o] = LDT18(trow0 + 1, o);
        R2[o] = LDT18(trow0 + 2, o);
        R3[o] = LDT18(trow0 + 3, o);
    }
    {
        floatx4 aA, aB;
        conv9x2_last(R0, R1, R2, R3, afl, zc, aA, aB);
        if (q == 0) {
            size_t o0 = (size_t)b * LL + (size_t)(x0 + trow0 + 0) * L_ + (y0 + m);
            size_t o1 = (size_t)b * LL + (size_t)(x0 + trow0 + 1) * L_ + (y0 + m);
            float v0 = 0.5f * aA[0];
            float v1 = 0.5f * aB[0];
            if (mode == 0) { out[o0] = v0;           out[o1] = v1;           }
            else           { out[o0] = out[o0] - v0; out[o1] = out[o1] - v1; }
        }
    }
    #pragma unroll
    for (int o = 0; o < 3; ++o) {
        R4[o] = LDT18(trow0 + 4, o);
        R5[o] = LDT18(trow0 + 5, o);
    }
    {
        floatx4 aA, aB;
        conv9x2_last(R2, R3, R4, R5, afl, zc, aA, aB);
        if (q == 0) {
            size_t o0 = (size_t)b * LL + (size_t)(x0 + trow0 + 2) * L_ + (y0 + m);
            size_t o1 = (size_t)b * LL + (size_t)(x0 + trow0 + 3) * L_ + (y0 + m);
            float v0 = 0.5f * aA[0];
            float v1 = 0.5f * aB[0];
            if (mode == 0) { out[o0] = v0;           out[o1] = v1;           }
            else           { out[o0] = out[o0] - v0; out[o1] = out[o1] - v1; }
        }
    }
#undef LDT18
}

extern "C" void kernel_launch(void* const* d_in, const int* in_sizes, int n_in,
                              void* d_out, int out_size, void* d_ws, size_t ws_size,
                              hipStream_t stream) {
    const float* x      = (const float*)d_in[0];
    const float* ai     = (const float*)d_in[1];
    const float* ao     = (const float*)d_in[2];
    const float* a      = (const float*)d_in[3];
    const float* bi     = (const float*)d_in[4];
    const float* bo     = (const float*)d_in[5];
    const float* b      = (const float*)d_in[6];
    const float* ci     = (const float*)d_in[7];
    const float* co     = (const float*)d_in[8];
    const float* c      = (const float*)d_in[9];
    const float* bias_i = (const float*)d_in[10];
    const float* bias   = (const float*)d_in[11];
    float* out = (float*)d_out;

    unsigned short* hA = (unsigned short*)d_ws;
    unsigned short* hB = hA + ELEMS;

    dim3 grid(B_ * 256), blk(256);
    const int WW = W_ * W_;
    for (int s = 0; s < 2; ++s) {
        float scale = s ? -1.0f : 1.0f;
        kern_front<<<grid, blk, 0, stream>>>(x, scale,
            ci, bi, ai, bias_i,
            c, b, a, bias,
            c + WW, b + WW, a + WW, bias + W_,
            hB);
        kern_mid2<<<grid, blk, 0, stream>>>(hB,
            c + 2*WW, b + 2*WW, a + 2*WW, bias + 2*W_,
            c + 3*WW, b + 3*WW, a + 3*WW, bias + 3*W_,
            hA);
        kern_last<<<grid, blk, 0, stream>>>(hA, co, bo, ao, out, s);
    }
}

// Round 15
// 700.293 us; speedup vs baseline: 1.0334x; 1.0089x over previous
//
#include <hip/hip_runtime.h>
#include <hip/hip_bf16.h>

#define B_ 32
#define L_ 256
#define W_ 32
#define TILE 16
#define PSTR 40          // shorts per (row,col) position: 80B = 5*16B, b128-aligned
#define LL (L_*L_)
#define ELEMS ((size_t)B_ * W_ * LL)

typedef float    floatx4 __attribute__((ext_vector_type(4)));
typedef float    floatx2 __attribute__((ext_vector_type(2)));
typedef short    shortx8 __attribute__((ext_vector_type(8)));
typedef unsigned uintx2  __attribute__((ext_vector_type(2)));
typedef unsigned uintx4  __attribute__((ext_vector_type(4)));

typedef const __attribute__((address_space(1))) unsigned guint_t;
typedef __attribute__((address_space(3))) unsigned luint_t;

// async global->LDS DMA, 16B per lane; LDS image linear in granule index.
// NOTE (r10 lesson): EXEC mask must be a contiguous prefix of the wave.
__device__ __forceinline__ void lds_dma16(const unsigned short* src, unsigned short* dst) {
    __builtin_amdgcn_global_load_lds((guint_t*)src, (luint_t*)dst, 16, 0, 0);
}

__device__ __forceinline__ floatx2 fma2(floatx2 a, floatx2 b, floatx2 c) {
#if __has_builtin(__builtin_elementwise_fma)
    return __builtin_elementwise_fma(a, b, c);
#else
    return floatx2{fmaf(a.x, b.x, c.x), fmaf(a.y, b.y, c.y)};
#endif
}

#if __has_builtin(__builtin_amdgcn_cvt_pk_bf16_f32)
__device__ __forceinline__ unsigned pack_bf2(float a, float b) {
    auto v = __builtin_amdgcn_cvt_pk_bf16_f32(a, b);
    return __builtin_bit_cast(unsigned, v);
}
#else
__device__ __forceinline__ unsigned pack_bf2(float a, float b) {
    unsigned ua = __float_as_uint(a);
    unsigned ub = __float_as_uint(b);
    ua += 0x7fffu + ((ua >> 16) & 1u);
    ub += 0x7fffu + ((ub >> 16) & 1u);
    return (ua >> 16) | (ub & 0xffff0000u);
}
#endif

// ---- scalar fast GELU (round-1-proven arithmetic, REQUIRED in kern_front:
// packed-float2 gelu miscompiles in the kern_front context — r9/r12/r14) ----
__device__ __forceinline__ float gelu_fast(float x) {
    float x2 = x * x;
    float inner = fmaf(0.044715f * x2, x, x);
    float e = __builtin_amdgcn_exp2f(inner * -2.3022082299446597f);
    return x * __builtin_amdgcn_rcpf(1.0f + e);
}

// ---- packed GELU pair (proven in kern_mid2/kern_last ONLY) ----
__device__ __forceinline__ unsigned gelu2_pack(floatx2 x) {
    floatx2 x2    = x * x;
    floatx2 t     = x2 * 0.044715f;
    floatx2 inner = fma2(t, x, x);
    floatx2 z     = inner * -2.3022082299446597f;
    float e0 = __builtin_amdgcn_exp2f(z.x);
    float e1 = __builtin_amdgcn_exp2f(z.y);
    float r0 = __builtin_amdgcn_rcpf(1.0f + e0);
    float r1 = __builtin_amdgcn_rcpf(1.0f + e1);
    floatx2 g = x * floatx2{r0, r1};
    return pack_bf2(g.x, g.y);
}

__device__ __forceinline__ int swizzle_blk(int p) {
    return (p & 7) * 1024 + (p >> 3);
}

// ======================= round-1-style helpers (kern_front only) =======================
// 9-tap dual-half MFMA conv, accumulator initialized from bv arrays (round-1 text).
__device__ __forceinline__ void conv9_v1(
        const shortx8& t00, const shortx8& t01, const shortx8& t02,
        const shortx8& t10, const shortx8& t11, const shortx8& t12,
        const shortx8& t20, const shortx8& t21, const shortx8& t22,
        const shortx8 af[3][2], const float bv[2][4], floatx4 acc[2]) {
    #pragma unroll
    for (int h = 0; h < 2; ++h) {
        acc[h] = floatx4{bv[h][0], bv[h][1], bv[h][2], bv[h][3]};
        acc[h] = __builtin_amdgcn_mfma_f32_16x16x32_bf16(af[0][h], t11, acc[h], 0, 0, 0);
        acc[h] = __builtin_amdgcn_mfma_f32_16x16x32_bf16(af[1][h], t01, acc[h], 0, 0, 0);
        acc[h] = __builtin_amdgcn_mfma_f32_16x16x32_bf16(af[1][h], t21, acc[h], 0, 0, 0);
        acc[h] = __builtin_amdgcn_mfma_f32_16x16x32_bf16(af[1][h], t10, acc[h], 0, 0, 0);
        acc[h] = __builtin_amdgcn_mfma_f32_16x16x32_bf16(af[1][h], t12, acc[h], 0, 0, 0);
        acc[h] = __builtin_amdgcn_mfma_f32_16x16x32_bf16(af[2][h], t00, acc[h], 0, 0, 0);
        acc[h] = __builtin_amdgcn_mfma_f32_16x16x32_bf16(af[2][h], t02, acc[h], 0, 0, 0);
        acc[h] = __builtin_amdgcn_mfma_f32_16x16x32_bf16(af[2][h], t20, acc[h], 0, 0, 0);
        acc[h] = __builtin_amdgcn_mfma_f32_16x16x32_bf16(af[2][h], t22, acc[h], 0, 0, 0);
    }
}

__device__ __forceinline__ void gelu_pack4_v1(const floatx4 acc[2], unsigned d[4]) {
    d[0] = pack_bf2(gelu_fast(acc[0][0]), gelu_fast(acc[0][1]));
    d[1] = pack_bf2(gelu_fast(acc[0][2]), gelu_fast(acc[0][3]));
    d[2] = pack_bf2(gelu_fast(acc[1][0]), gelu_fast(acc[1][1]));
    d[3] = pack_bf2(gelu_fast(acc[1][2]), gelu_fast(acc[1][3]));
}

__device__ __forceinline__ void build_afrag_v1(
        const float* wc, const float* wb, const float* wa, const float* bias,
        int m, int q, shortx8 af[3][2], float bv[2][4]) {
    const float* wm[3] = { wc, wb, wa };
    #pragma unroll
    for (int f = 0; f < 3; ++f)
      #pragma unroll
      for (int h = 0; h < 2; ++h) {
        const float* row = wm[f] + (h*16 + m) * W_ + q*8;
        floatx4 r0 = *(const floatx4*)(row);
        floatx4 r1 = *(const floatx4*)(row + 4);
        union { shortx8 s; unsigned u[4]; } w;
        w.u[0] = pack_bf2(r0.x, r0.y);
        w.u[1] = pack_bf2(r0.z, r0.w);
        w.u[2] = pack_bf2(r1.x, r1.y);
        w.u[3] = pack_bf2(r1.z, r1.w);
        af[f][h] = w.s;
      }
    #pragma unroll
    for (int h = 0; h < 2; ++h)
      #pragma unroll
      for (int r = 0; r < 4; ++r)
        bv[h][r] = bias[h*16 + q*4 + r];
}

// ======================= round-11-style helpers (mid2/last) =======================
// 9-tap dual-half MFMA conv; bias enters as the C operand of the FIRST mfma.
__device__ __forceinline__ void conv9(
        const shortx8& t00, const shortx8& t01, const shortx8& t02,
        const shortx8& t10, const shortx8& t11, const shortx8& t12,
        const shortx8& t20, const shortx8& t21, const shortx8& t22,
        const shortx8 af[3][2], const floatx4 bvv[2], floatx4 acc[2]) {
    #pragma unroll
    for (int h = 0; h < 2; ++h) {
        acc[h] = __builtin_amdgcn_mfma_f32_16x16x32_bf16(af[0][h], t11, bvv[h], 0, 0, 0);
        acc[h] = __builtin_amdgcn_mfma_f32_16x16x32_bf16(af[1][h], t01, acc[h], 0, 0, 0);
        acc[h] = __builtin_amdgcn_mfma_f32_16x16x32_bf16(af[1][h], t21, acc[h], 0, 0, 0);
        acc[h] = __builtin_amdgcn_mfma_f32_16x16x32_bf16(af[1][h], t10, acc[h], 0, 0, 0);
        acc[h] = __builtin_amdgcn_mfma_f32_16x16x32_bf16(af[1][h], t12, acc[h], 0, 0, 0);
        acc[h] = __builtin_amdgcn_mfma_f32_16x16x32_bf16(af[2][h], t00, acc[h], 0, 0, 0);
        acc[h] = __builtin_amdgcn_mfma_f32_16x16x32_bf16(af[2][h], t02, acc[h], 0, 0, 0);
        acc[h] = __builtin_amdgcn_mfma_f32_16x16x32_bf16(af[2][h], t20, acc[h], 0, 0, 0);
        acc[h] = __builtin_amdgcn_mfma_f32_16x16x32_bf16(af[2][h], t22, acc[h], 0, 0, 0);
    }
}

// Dual-site conv: per-site MFMA order identical to conv9; bias folded into first mfma.
__device__ __forceinline__ void conv9x2(
        const shortx8 r0[3], const shortx8 r1[3],
        const shortx8 r2[3], const shortx8 r3[3],
        const shortx8 af[3][2], const floatx4 bvv[2],
        floatx4 accA[2], floatx4 accB[2]) {
    const shortx8* ra[3] = { r0, r1, r2 };
    const shortx8* rb[3] = { r1, r2, r3 };
    const int F[9] = {0,1,1,1,1,2,2,2,2};
    const int R[9] = {1,0,2,1,1,0,0,2,2};
    const int C[9] = {1,1,1,0,2,0,2,0,2};
    #pragma unroll
    for (int k = 0; k < 9; ++k)
      #pragma unroll
      for (int h = 0; h < 2; ++h) {
        accA[h] = __builtin_amdgcn_mfma_f32_16x16x32_bf16(af[F[k]][h], ra[R[k]][C[k]],
                      (k == 0) ? bvv[h] : accA[h], 0, 0, 0);
        accB[h] = __builtin_amdgcn_mfma_f32_16x16x32_bf16(af[F[k]][h], rb[R[k]][C[k]],
                      (k == 0) ? bvv[h] : accB[h], 0, 0, 0);
      }
}

// Dual-site conv for the last layer (single half, zero C), same op table.
__device__ __forceinline__ void conv9x2_last(
        const shortx8 r0[3], const shortx8 r1[3],
        const shortx8 r2[3], const shortx8 r3[3],
        const shortx8 afl[3], const floatx4& zc, floatx4& accA, floatx4& accB) {
    const shortx8* ra[3] = { r0, r1, r2 };
    const shortx8* rb[3] = { r1, r2, r3 };
    const int F[9] = {0,1,1,1,1,2,2,2,2};
    const int R[9] = {1,0,2,1,1,0,0,2,2};
    const int C[9] = {1,1,1,0,2,0,2,0,2};
    #pragma unroll
    for (int k = 0; k < 9; ++k) {
        accA = __builtin_amdgcn_mfma_f32_16x16x32_bf16(afl[F[k]], ra[R[k]][C[k]],
                   (k == 0) ? zc : accA, 0, 0, 0);
        accB = __builtin_amdgcn_mfma_f32_16x16x32_bf16(afl[F[k]], rb[R[k]][C[k]],
                   (k == 0) ? zc : accB, 0, 0, 0);
    }
}

__device__ __forceinline__ void gelu_pack4(const floatx4 acc[2], unsigned d[4]) {
    d[0] = gelu2_pack(floatx2{acc[0][0], acc[0][1]});
    d[1] = gelu2_pack(floatx2{acc[0][2], acc[0][3]});
    d[2] = gelu2_pack(floatx2{acc[1][0], acc[1][1]});
    d[3] = gelu2_pack(floatx2{acc[1][2], acc[1][3]});
}

__device__ __forceinline__ void build_afrag(
        const float* wc, const float* wb, const float* wa, const float* bias,
        int m, int q, shortx8 af[3][2], floatx4 bvv[2]) {
    const float* wm[3] = { wc, wb, wa };
    #pragma unroll
    for (int f = 0; f < 3; ++f)
      #pragma unroll
      for (int h = 0; h < 2; ++h) {
        const float* row = wm[f] + (h*16 + m) * W_ + q*8;
        floatx4 r0 = *(const floatx4*)(row);
        floatx4 r1 = *(const floatx4*)(row + 4);
        union { shortx8 s; unsigned u[4]; } w;
        w.u[0] = pack_bf2(r0.x, r0.y);
        w.u[1] = pack_bf2(r0.z, r0.w);
        w.u[2] = pack_bf2(r1.x, r1.y);
        w.u[3] = pack_bf2(r1.z, r1.w);
        af[f][h] = w.s;
      }
    #pragma unroll
    for (int h = 0; h < 2; ++h)
        bvv[h] = *(const floatx4*)(bias + h*16 + q*4);
}

// ---------------- front: first layer (1->32, VALU, in-LDS) + mid0 + mid1 ----------------
// ROUND-13 TEXT (passed at 706.5 µs): round-1 scalar arithmetic throughout kern_front.
// xs (rr,cc) rr,cc in 0..21 <-> global (x0+rr-3, y0+cc-3)  [f32, LDS, stride 23]
// tile2 pos (r,c) r,c in 0..19 <-> global (x0+r-2, y0+c-2), first-layer output (32ch bf16)
// mid0: 18x18 sites (shifted in place); mid1: 16x16 sites -> global hout.
__global__ __launch_bounds__(256, 4) void kern_front(
        const float* __restrict__ x, float scale,
        const float* __restrict__ ci, const float* __restrict__ bi,
        const float* __restrict__ ai, const float* __restrict__ bias_i,
        const float* __restrict__ wc1, const float* __restrict__ wb1,
        const float* __restrict__ wa1, const float* __restrict__ bias1,
        const float* __restrict__ wc2, const float* __restrict__ wb2,
        const float* __restrict__ wa2, const float* __restrict__ bias2,
        unsigned short* __restrict__ hout) {
    __shared__ unsigned short tile2[400 * PSTR];     // 32000 B
    __shared__ float xs[22 * 23];                    // 2024 B
    __shared__ float wC[W_], wB[W_], wA[W_], bs[W_];

    const int tid = threadIdx.x;
    const int blk = swizzle_blk(blockIdx.x);
    const int b  = blk >> 8;
    const int t  = blk & 255;
    const int x0 = (t >> 4) * TILE;
    const int y0 = (t & 15) * TILE;

    if (tid < W_) { wC[tid] = ci[tid]; wB[tid] = bi[tid]; wA[tid] = ai[tid]; bs[tid] = bias_i[tid]; }

    const float* xb = x + (size_t)b * LL;
    #pragma unroll
    for (int ss = 0; ss < 2; ++ss) {
        int idx = tid + ss * 256;
        if (idx < 484) {
            int r = (idx * 2979) >> 16;      // idx / 22
            int c = idx - r * 22;
            int gx = (x0 + r - 3) & 255;
            int gy = (y0 + c - 3) & 255;
            xs[r * 23 + c] = scale * xb[gx * L_ + gy];
        }
    }
    __syncthreads();

    // ---- first layer: 400 sites, 32 channels each, pure VALU (round-1 scalar form) ----
    #pragma unroll
    for (int ss = 0; ss < 2; ++ss) {
        int idx = tid + ss * 256;
        if (idx < 400) {
            int i = (idx * 3277) >> 16;      // idx / 20
            int j = idx - i * 20;
            const float* p0 = &xs[i * 23 + j];
            float ctr = p0[24];
            float nb  = p0[1] + p0[47] + p0[23] + p0[25];
            float dg  = p0[0] + p0[2] + p0[46] + p0[48];
            unsigned od[16];
            #pragma unroll
            for (int o = 0; o < 16; ++o) {
                float v0 = gelu_fast(wC[2*o]*ctr + wB[2*o]*nb + wA[2*o]*dg + bs[2*o]);
                float v1 = gelu_fast(wC[2*o+1]*ctr + wB[2*o+1]*nb + wA[2*o+1]*dg + bs[2*o+1]);
                od[o] = pack_bf2(v0, v1);
            }
            unsigned* dst = (unsigned*)(tile2 + idx * PSTR);
            *(uintx4*)(dst)      = uintx4{od[0],  od[1],  od[2],  od[3]};
            *(uintx4*)(dst + 4)  = uintx4{od[4],  od[5],  od[6],  od[7]};
            *(uintx4*)(dst + 8)  = uintx4{od[8],  od[9],  od[10], od[11]};
            *(uintx4*)(dst + 12) = uintx4{od[12], od[13], od[14], od[15]};
        }
    }

    const int lane = tid & 63;
    const int wv   = tid >> 6;
    const int m    = lane & 15;
    const int q    = lane >> 4;

    shortx8 afrag[3][2];
    float bv[2][4];
    build_afrag_v1(wc1, wb1, wa1, bias1, m, q, afrag, bv);

    __syncthreads();    // first-layer field complete

#define LDT(tr, off) (*(const shortx8*)(tile2 + (((tr)*20 + m + (off)))*PSTR + q*8))

    // ---- mid0 main: wave wv -> site rows 4wv..4wv+3, cols m (0..15), sliding ring ----
    const int trow0 = wv * 4;
    shortx8 W[3][3];
    #pragma unroll
    for (int i = 0; i < 3; ++i) {
        W[i][0] = LDT(trow0 + i, 0);
        W[i][1] = LDT(trow0 + i, 1);
        W[i][2] = LDT(trow0 + i, 2);
    }
    unsigned heldA[2][4];
    #pragma unroll
    for (int rr = 0; rr < 4; ++rr) {
        const int top = rr % 3, mid = (rr + 1) % 3, bot = (rr + 2) % 3;
        floatx4 acc[2];
        conv9_v1(W[top][0], W[top][1], W[top][2],
                 W[mid][0], W[mid][1], W[mid][2],
                 W[bot][0], W[bot][1], W[bot][2], afrag, bv, acc);
        unsigned d[4];
        gelu_pack4_v1(acc, d);
        if (rr < 2) {
            heldA[rr][0] = d[0]; heldA[rr][1] = d[1];
            heldA[rr][2] = d[2]; heldA[rr][3] = d[3];
        } else {
            // rows 4wv+2,4wv+3 cols 0..15: proven unread by any concurrent wave
            unsigned short* wp = tile2 + ((trow0 + rr)*20 + m)*PSTR + q*4;
            *(uintx2*)(wp)      = uintx2{d[0], d[1]};
            *(uintx2*)(wp + 16) = uintx2{d[2], d[3]};
        }
        if (rr < 3) {
            W[top][0] = LDT(trow0 + rr + 3, 0);
            W[top][1] = LDT(trow0 + rr + 3, 1);
            W[top][2] = LDT(trow0 + rr + 3, 2);
        }
    }

    // ---- mid0 edges: rows 16,17 (waves 0,1) / cols 16,17 (waves 2,3) + corners (wave 2) ----
    int er0, ec0;
    if (wv == 0)      { er0 = 16; ec0 = m;  }
    else if (wv == 1) { er0 = 17; ec0 = m;  }
    else if (wv == 2) { er0 = m;  ec0 = 16; }
    else              { er0 = m;  ec0 = 17; }
    unsigned heldE[4];
    {
        shortx8 T[3][3];
        #pragma unroll
        for (int i = 0; i < 3; ++i)
          #pragma unroll
          for (int o = 0; o < 3; ++o)
            T[i][o] = *(const shortx8*)(tile2 + ((er0 + i)*20 + ec0 + o)*PSTR + q*8);
        floatx4 acc[2];
        conv9_v1(T[0][0], T[0][1], T[0][2], T[1][0], T[1][1], T[1][2],
                 T[2][0], T[2][1], T[2][2], afrag, bv, acc);
        gelu_pack4_v1(acc, heldE);
    }
    const int heldEoff = (er0*20 + ec0)*PSTR + q*4;

    unsigned heldC[4];
    int heldCoff = 0;
    if (wv == 2) {
        int sr = 16 + ((m >> 1) & 1);
        int sc = 16 + (m & 1);
        shortx8 T[3][3];
        #pragma unroll
        for (int i = 0; i < 3; ++i)
          #pragma unroll
          for (int o = 0; o < 3; ++o)
            T[i][o] = *(const shortx8*)(tile2 + ((sr + i)*20 + sc + o)*PSTR + q*8);
        floatx4 acc[2];
        conv9_v1(T[0][0], T[0][1], T[0][2], T[1][0], T[1][1], T[1][2],
                 T[2][0], T[2][1], T[2][2], afrag, bv, acc);
        gelu_pack4_v1(acc, heldC);
        heldCoff = (sr*20 + sc)*PSTR + q*4;
    }

    __syncthreads();   // all mid0 tap reads complete

    #pragma unroll
    for (int rr = 0; rr < 2; ++rr) {
        unsigned short* wp = tile2 + ((trow0 + rr)*20 + m)*PSTR + q*4;
        *(uintx2*)(wp)      = uintx2{heldA[rr][0], heldA[rr][1]};
        *(uintx2*)(wp + 16) = uintx2{heldA[rr][2], heldA[rr][3]};
    }
    {
        unsigned short* wp = tile2 + heldEoff;
        *(uintx2*)(wp)      = uintx2{heldE[0], heldE[1]};
        *(uintx2*)(wp + 16) = uintx2{heldE[2], heldE[3]};
    }
    if (wv == 2 && m < 4) {
        unsigned short* wp = tile2 + heldCoff;
        *(uintx2*)(wp)      = uintx2{heldC[0], heldC[1]};
        *(uintx2*)(wp + 16) = uintx2{heldC[2], heldC[3]};
    }

    build_afrag_v1(wc2, wb2, wa2, bias2, m, q, afrag, bv);

    __syncthreads();   // mid0 field complete at positions (0..17)^2

    // ---- mid1: wave wv -> site rows 4wv..4wv+3, cols m; out to global; sliding ring ----
    unsigned short* outb = hout + ((size_t)b << 21);
    #pragma unroll
    for (int i = 0; i < 3; ++i) {
        W[i][0] = LDT(trow0 + i, 0);
        W[i][1] = LDT(trow0 + i, 1);
        W[i][2] = LDT(trow0 + i, 2);
    }
    #pragma unroll
    for (int rr = 0; rr < 4; ++rr) {
        const int top = rr % 3, mid = (rr + 1) % 3, bot = (rr + 2) % 3;
        floatx4 acc[2];
        conv9_v1(W[top][0], W[top][1], W[top][2],
                 W[mid][0], W[mid][1], W[mid][2],
                 W[bot][0], W[bot][1], W[bot][2], afrag, bv, acc);
        unsigned d[4];
        gelu_pack4_v1(acc, d);
        unsigned short* dst = outb + ((((unsigned)(x0 + trow0 + rr) << 8) | (unsigned)(y0 + m)) << 5) + q*4;
        *(uintx2*)(dst)      = uintx2{d[0], d[1]};
        *(uintx2*)(dst + 16) = uintx2{d[2], d[3]};
        if (rr < 3) {
            W[top][0] = LDT(trow0 + rr + 3, 0);
            W[top][1] = LDT(trow0 + rr + 3, 1);
            W[top][2] = LDT(trow0 + rr + 3, 2);
        }
    }
#undef LDT
}

// ---------------- fused middle-layer pair (mid2+mid3): unchanged from round 13 ----------------
__global__ __launch_bounds__(256, 4) void kern_mid2(
        const unsigned short* __restrict__ hin,
        const float* __restrict__ wc1, const float* __restrict__ wb1,
        const float* __restrict__ wa1, const float* __restrict__ bias1,
        const float* __restrict__ wc2, const float* __restrict__ wb2,
        const float* __restrict__ wa2, const float* __restrict__ bias2,
        unsigned short* __restrict__ hout) {
    __shared__ unsigned short tile2[400 * PSTR];     // 32000 B

    const int tid = threadIdx.x;
    const int blk = swizzle_blk(blockIdx.x);
    const int b  = blk >> 8;
    const int t  = blk & 255;
    const int x0 = (t >> 4) * TILE;
    const int y0 = (t & 15) * TILE;

    const unsigned short* hb = hin + ((size_t)b << 21);

    // ---- stage: async DMA, 2000 granules of 16B; LDS offset = j*16 (linear) ----
    #pragma unroll
    for (int jj = 0; jj < 8; ++jj) {
        int j = tid + jj * 256;
        if (j < 2000) {
            int pos = (j * 3277) >> 14;     // j / 5
            int qtr = j - pos * 5;          // 0..4 (4 = pad granule)
            int qe  = qtr < 4 ? qtr : 3;    // clamp pad source in-bounds
            int r = (pos * 3277) >> 16;     // pos / 20
            int c = pos - r * 20;
            int gx = (x0 + r - 2) & 255;
            int gy = (y0 + c - 2) & 255;
            const unsigned short* src = hb + ((((unsigned)gx << 8) | (unsigned)gy) << 5) + qe*8;
            lds_dma16(src, tile2 + (size_t)j * 8);
        }
    }

    const int lane = tid & 63;
    const int wv   = tid >> 6;
    const int m    = lane & 15;
    const int q    = lane >> 4;

    shortx8 afrag[3][2];
    floatx4 bvv[2];
    build_afrag(wc1, wb1, wa1, bias1, m, q, afrag, bvv);

    __syncthreads();    // drains DMA (vmcnt) + weight loads

#define LDT(tr, off) (*(const shortx8*)(tile2 + (((tr)*20 + m + (off)))*PSTR + q*8))

    const int trow0 = wv * 4;
    shortx8 R0[3], R1[3], R2[3], R3[3], R4[3], R5[3];
    #pragma unroll
    for (int o = 0; o < 3; ++o) {
        R0[o] = LDT(trow0 + 0, o);
        R1[o] = LDT(trow0 + 1, o);
        R2[o] = LDT(trow0 + 2, o);
        R3[o] = LDT(trow0 + 3, o);
    }
    unsigned heldA[2][4];
    {
        floatx4 accA[2], accB[2];
        conv9x2(R0, R1, R2, R3, afrag, bvv, accA, accB);
        gelu_pack4(accA, heldA[0]);
        gelu_pack4(accB, heldA[1]);
    }
    #pragma unroll
    for (int o = 0; o < 3; ++o) {
        R4[o] = LDT(trow0 + 4, o);
        R5[o] = LDT(trow0 + 5, o);
    }
    {
        floatx4 accA[2], accB[2];
        conv9x2(R2, R3, R4, R5, afrag, bvv, accA, accB);
        unsigned dA[4], dB[4];
        gelu_pack4(accA, dA);
        gelu_pack4(accB, dB);
        // rows 4wv+2,4wv+3 cols 0..15: proven unread by any concurrent wave
        unsigned short* wpA = tile2 + ((trow0 + 2)*20 + m)*PSTR + q*4;
        *(uintx2*)(wpA)      = uintx2{dA[0], dA[1]};
        *(uintx2*)(wpA + 16) = uintx2{dA[2], dA[3]};
        unsigned short* wpB = tile2 + ((trow0 + 3)*20 + m)*PSTR + q*4;
        *(uintx2*)(wpB)      = uintx2{dB[0], dB[1]};
        *(uintx2*)(wpB + 16) = uintx2{dB[2], dB[3]};
    }

    int er0, ec0;
    if (wv == 0)      { er0 = 16; ec0 = m;  }
    else if (wv == 1) { er0 = 17; ec0 = m;  }
    else if (wv == 2) { er0 = m;  ec0 = 16; }
    else              { er0 = m;  ec0 = 17; }
    unsigned heldE[4];
    {
        shortx8 T[3][3];
        #pragma unroll
        for (int i = 0; i < 3; ++i)
          #pragma unroll
          for (int o = 0; o < 3; ++o)
            T[i][o] = *(const shortx8*)(tile2 + ((er0 + i)*20 + ec0 + o)*PSTR + q*8);
        floatx4 acc[2];
        conv9(T[0][0], T[0][1], T[0][2], T[1][0], T[1][1], T[1][2],
              T[2][0], T[2][1], T[2][2], afrag, bvv, acc);
        gelu_pack4(acc, heldE);
    }
    const int heldEoff = (er0*20 + ec0)*PSTR + q*4;

    unsigned heldC[4];
    int heldCoff = 0;
    if (wv == 2) {
        int sr = 16 + ((m >> 1) & 1);
        int sc = 16 + (m & 1);
        shortx8 T[3][3];
        #pragma unroll
        for (int i = 0; i < 3; ++i)
          #pragma unroll
          for (int o = 0; o < 3; ++o)
            T[i][o] = *(const shortx8*)(tile2 + ((sr + i)*20 + sc + o)*PSTR + q*8);
        floatx4 acc[2];
        conv9(T[0][0], T[0][1], T[0][2], T[1][0], T[1][1], T[1][2],
              T[2][0], T[2][1], T[2][2], afrag, bvv, acc);
        gelu_pack4(acc, heldC);
        heldCoff = (sr*20 + sc)*PSTR + q*4;
    }

    __syncthreads();   // all layer-A tap reads complete

    #pragma unroll
    for (int rr = 0; rr < 2; ++rr) {
        unsigned short* wp = tile2 + ((trow0 + rr)*20 + m)*PSTR + q*4;
        *(uintx2*)(wp)      = uintx2{heldA[rr][0], heldA[rr][1]};
        *(uintx2*)(wp + 16) = uintx2{heldA[rr][2], heldA[rr][3]};
    }
    {
        unsigned short* wp = tile2 + heldEoff;
        *(uintx2*)(wp)      = uintx2{heldE[0], heldE[1]};
        *(uintx2*)(wp + 16) = uintx2{heldE[2], heldE[3]};
    }
    if (wv == 2 && m < 4) {
        unsigned short* wp = tile2 + heldCoff;
        *(uintx2*)(wp)      = uintx2{heldC[0], heldC[1]};
        *(uintx2*)(wp + 16) = uintx2{heldC[2], heldC[3]};
    }

    build_afrag(wc2, wb2, wa2, bias2, m, q, afrag, bvv);

    __syncthreads();   // mid-k+1 field complete at positions (0..17)^2

    unsigned short* outb = hout + ((size_t)b << 21);
    #pragma unroll
    for (int o = 0; o < 3; ++o) {
        R0[o] = LDT(trow0 + 0, o);
        R1[o] = LDT(trow0 + 1, o);
        R2[o] = LDT(trow0 + 2, o);
        R3[o] = LDT(trow0 + 3, o);
    }
    {
        floatx4 accA[2], accB[2];
        conv9x2(R0, R1, R2, R3, afrag, bvv, accA, accB);
        unsigned dA[4], dB[4];
        gelu_pack4(accA, dA);
        gelu_pack4(accB, dB);
        unsigned short* dstA = outb + ((((unsigned)(x0 + trow0 + 0) << 8) | (unsigned)(y0 + m)) << 5) + q*4;
        *(uintx2*)(dstA)      = uintx2{dA[0], dA[1]};
        *(uintx2*)(dstA + 16) = uintx2{dA[2], dA[3]};
        unsigned short* dstB = outb + ((((unsigned)(x0 + trow0 + 1) << 8) | (unsigned)(y0 + m)) << 5) + q*4;
        *(uintx2*)(dstB)      = uintx2{dB[0], dB[1]};
        *(uintx2*)(dstB + 16) = uintx2{dB[2], dB[3]};
    }
    #pragma unroll
    for (int o = 0; o < 3; ++o) {
        R4[o] = LDT(trow0 + 4, o);
        R5[o] = LDT(trow0 + 5, o);
    }
    {
        floatx4 accA[2], accB[2];
        conv9x2(R2, R3, R4, R5, afrag, bvv, accA, accB);
        unsigned dA[4], dB[4];
        gelu_pack4(accA, dA);
        gelu_pack4(accB, dB);
        unsigned short* dstA = outb + ((((unsigned)(x0 + trow0 + 2) << 8) | (unsigned)(y0 + m)) << 5) + q*4;
        *(uintx2*)(dstA)      = uintx2{dA[0], dA[1]};
        *(uintx2*)(dstA + 16) = uintx2{dA[2], dA[3]};
        unsigned short* dstB = outb + ((((unsigned)(x0 + trow0 + 3) << 8) | (unsigned)(y0 + m)) << 5) + q*4;
        *(uintx2*)(dstB)      = uintx2{dB[0], dB[1]};
        *(uintx2*)(dstB + 16) = uintx2{dB[2], dB[3]};
    }
#undef LDT
}

// ---------------- last layer: unchanged from round 13 ----------------
__global__ __launch_bounds__(256, 6) void kern_last(
        const unsigned short* __restrict__ hin,
        const float* __restrict__ co, const float* __restrict__ bo,
        const float* __restrict__ ao,
        float* __restrict__ out, int mode) {
    __shared__ unsigned short tile2[324 * PSTR];     // 25920 B
    const int tid = threadIdx.x;
    const int blk = swizzle_blk(blockIdx.x);
    const int b  = blk >> 8;
    const int t  = blk & 255;
    const int x0 = (t >> 4) * TILE;
    const int y0 = (t & 15) * TILE;

    const unsigned short* hb = hin + ((size_t)b << 21);
    // stage 18x18 positions (halo 1): 1620 DMA granules of 16B (5/pos, pad clamped)
    #pragma unroll
    for (int jj = 0; jj < 7; ++jj) {
        int j = tid + jj * 256;
        if (j < 1620) {
            int pos = (j * 3277) >> 14;     // j / 5
            int qtr = j - pos * 5;
            int qe  = qtr < 4 ? qtr : 3;
            int r = (pos * 3641) >> 16;     // pos / 18
            int c = pos - r * 18;
            int gx = (x0 + r - 1) & 255;
            int gy = (y0 + c - 1) & 255;
            const unsigned short* src = hb + ((((unsigned)gx << 8) | (unsigned)gy) << 5) + qe*8;
            lds_dma16(src, tile2 + (size_t)j * 8);
        }
    }

    const int lane = tid & 63;
    const int wv   = tid >> 6;
    const int m    = lane & 15;
    const int q    = lane >> 4;

    const float* wm[3] = { co, bo, ao };
    shortx8 afl[3];
    float z = (m == 0) ? 1.0f : 0.0f;
    #pragma unroll
    for (int f = 0; f < 3; ++f) {
        const float* row = wm[f] + q*8;
        floatx4 r0 = *(const floatx4*)(row);
        floatx4 r1 = *(const floatx4*)(row + 4);
        union { shortx8 s; unsigned u[4]; } w;
        w.u[0] = pack_bf2(r0.x * z, r0.y * z);
        w.u[1] = pack_bf2(r0.z * z, r0.w * z);
        w.u[2] = pack_bf2(r1.x * z, r1.y * z);
        w.u[3] = pack_bf2(r1.z * z, r1.w * z);
        afl[f] = w.s;
    }
    const floatx4 zc = {0.f, 0.f, 0.f, 0.f};

    __syncthreads();

#define LDT18(tr, off) (*(const shortx8*)(tile2 + (((tr)*18 + m + (off)))*PSTR + q*8))
    const int trow0 = wv * 4;
    shortx8 R0[3], R1[3], R2[3], R3[3], R4[3], R5[3];
    #pragma unroll
    for (int o = 0; o < 3; ++o) {
        R0[o] = LDT18(trow0 + 0, o);
        R1[o] = LDT18(trow0 + 1, o);
        R2[o] = LDT18(trow0 + 2, o);
        R3[o] = LDT18(trow0 + 3, o);
    }
    {
        floatx4 aA, aB;
        conv9x2_last(R0, R1, R2, R3, afl, zc, aA, aB);
        if (q == 0) {
            size_t o0 = (size_t)b * LL + (size_t)(x0 + trow0 + 0) * L_ + (y0 + m);
            size_t o1 = (size_t)b * LL + (size_t)(x0 + trow0 + 1) * L_ + (y0 + m);
            float v0 = 0.5f * aA[0];
            float v1 = 0.5f * aB[0];
            if (mode == 0) { out[o0] = v0;           out[o1] = v1;           }
            else           { out[o0] = out[o0] - v0; out[o1] = out[o1] - v1; }
        }
    }
    #pragma unroll
    for (int o = 0; o < 3; ++o) {
        R4[o] = LDT18(trow0 + 4, o);
        R5[o] = LDT18(trow0 + 5, o);
    }
    {
        floatx4 aA, aB;
        conv9x2_last(R2, R3, R4, R5, afl, zc, aA, aB);
        if (q == 0) {
            size_t o0 = (size_t)b * LL + (size_t)(x0 + trow0 + 2) * L_ + (y0 + m);
            size_t o1 = (size_t)b * LL + (size_t)(x0 + trow0 + 3) * L_ + (y0 + m);
            float v0 = 0.5f * aA[0];
            float v1 = 0.5f * aB[0];
            if (mode == 0) { out[o0] = v0;           out[o1] = v1;           }
            else           { out[o0] = out[o0] - v0; out[o1] = out[o1] - v1; }
        }
    }
#undef LDT18
}

extern "C" void kernel_launch(void* const* d_in, const int* in_sizes, int n_in,
                              void* d_out, int out_size, void* d_ws, size_t ws_size,
                              hipStream_t stream) {
    const float* x      = (const float*)d_in[0];
    const float* ai     = (const float*)d_in[1];
    const float* ao     = (const float*)d_in[2];
    const float* a      = (const float*)d_in[3];
    const float* bi     = (const float*)d_in[4];
    const float* bo     = (const float*)d_in[5];
    const float* b      = (const float*)d_in[6];
    const float* ci     = (const float*)d_in[7];
    const float* co     = (const float*)d_in[8];
    const float* c      = (const float*)d_in[9];
    const float* bias_i = (const float*)d_in[10];
    const float* bias   = (const float*)d_in[11];
    float* out = (float*)d_out;

    unsigned short* hA = (unsigned short*)d_ws;
    unsigned short* hB = hA + ELEMS;

    dim3 grid(B_ * 256), blk(256);
    const int WW = W_ * W_;
    for (int s = 0; s < 2; ++s) {
        float scale = s ? -1.0f : 1.0f;
        kern_front<<<grid, blk, 0, stream>>>(x, scale,
            ci, bi, ai, bias_i,
            c, b, a, bias,
            c + WW, b + WW, a + WW, bias + W_,
            hB);
        kern_mid2<<<grid, blk, 0, stream>>>(hB,
            c + 2*WW, b + 2*WW, a + 2*WW, bias + 2*W_,
            c + 3*WW, b + 3*WW, a + 3*WW, bias + 3*W_,
            hA);
        kern_last<<<grid, blk, 0, stream>>>(hA, co, bo, ao, out, s);
    }
}